// Round 1
// baseline (2584.676 us; speedup 1.0000x reference)
//
#include <hip/hip_runtime.h>

#define PI_F 3.14159265358979323846f
#define HWSZ 4096   // H*W
#define NPIX 8192   // B*H*W

// ---------------- wave reductions ----------------
__device__ __forceinline__ float wsum64(float v){
  #pragma unroll
  for (int m = 32; m >= 1; m >>= 1) v += __shfl_xor(v, m, 64);
  return v;
}
__device__ __forceinline__ float wsum32(float v){
  #pragma unroll
  for (int m = 16; m >= 1; m >>= 1) v += __shfl_xor(v, m, 64);
  return v;
}

// ---------------- layout transforms ----------------
// features (B,256,H,W) -> (B,H,W,256)
__global__ void k_nchw_to_nhwc(const float* __restrict__ in, float* __restrict__ out){
  __shared__ float tile[32][33];
  int b = blockIdx.z;
  int p0 = blockIdx.x * 32, c0 = blockIdx.y * 32;
  int tx = threadIdx.x, ty = threadIdx.y;
  #pragma unroll
  for (int i = ty; i < 32; i += 8)
    tile[i][tx] = in[((size_t)b*256 + c0 + i)*HWSZ + p0 + tx];
  __syncthreads();
  #pragma unroll
  for (int i = ty; i < 32; i += 8)
    out[((size_t)b*HWSZ + p0 + i)*256 + c0 + tx] = tile[tx][i];
}

// generic 2D transpose: in (R,Cn) -> out (Cn,R). R,Cn multiples of 32.
__global__ void k_transpose(const float* __restrict__ in, float* __restrict__ out, int R, int Cn){
  __shared__ float tile[32][33];
  int r0 = blockIdx.y * 32, c0 = blockIdx.x * 32;
  int tx = threadIdx.x, ty = threadIdx.y;
  #pragma unroll
  for (int i = ty; i < 32; i += 8)
    tile[i][tx] = in[(size_t)(r0 + i)*Cn + c0 + tx];
  __syncthreads();
  #pragma unroll
  for (int i = ty; i < 32; i += 8)
    out[(size_t)(c0 + i)*R + r0 + tx] = tile[tx][i];
}

// ---------------- 1) angle prediction ----------------
// conv 3x3 256->64 + relu. block: tid = w + 64*oi ; grid (h=64, o/4=16, b=2)
__global__ void k_apconv1(const float* __restrict__ feat, const float* __restrict__ w1,
    const float* __restrict__ b1, float* __restrict__ h1){
  int w = threadIdx.x & 63, oi = threadIdx.x >> 6;
  int h = blockIdx.x, o = blockIdx.y*4 + oi, b = blockIdx.z;
  float acc = b1[o];
  const float* wp = w1 + (size_t)o*256*9;
  const float* fpb = feat + (size_t)b*256*HWSZ;
  for (int c = 0; c < 256; ++c){
    const float* fc = fpb + (size_t)c*HWSZ;
    const float* wc = wp + c*9;
    #pragma unroll
    for (int ky = 0; ky < 3; ++ky){
      int y = h + ky - 1;
      if (y < 0 || y > 63) continue;
      const float* fr = fc + y*64;
      #pragma unroll
      for (int kx = 0; kx < 3; ++kx){
        int x = w + kx - 1;
        if (x >= 0 && x < 64)
          acc = fmaf(fr[x], wc[ky*3+kx], acc);
      }
    }
  }
  h1[((size_t)(b*64 + o)*64 + h)*64 + w] = fmaxf(acc, 0.f);
}

// 1x1 conv 64 -> 1 : angles per pixel
__global__ void k_angles(const float* __restrict__ h1, const float* __restrict__ w2,
    const float* __restrict__ b2, float* __restrict__ ang){
  int p = blockIdx.x*256 + threadIdx.x;
  int b = p >> 12, hw = p & 4095;
  float acc = b2[0];
  const float* hb = h1 + (size_t)b*64*HWSZ + hw;
  #pragma unroll 8
  for (int c = 0; c < 64; ++c)
    acc = fmaf(hb[(size_t)c*HWSZ], w2[c], acc);
  ang[p] = acc;
}

// ---------------- 2) angle encoding (one wave per pixel, lane = feature) ----------------
__global__ void k_angle_encode(const float* __restrict__ ang, const float* __restrict__ freq,
    const float* __restrict__ w1, const float* __restrict__ b1,
    const float* __restrict__ lng, const float* __restrict__ lnb,
    const float* __restrict__ w2, const float* __restrict__ b2,
    float* __restrict__ aemb){
  int lane = threadIdx.x & 63;
  int p = blockIdx.x * 4 + (threadIdx.x >> 6);
  float an = ang[p] * (2.0f / PI_F);
  int f = lane & 31;
  float ph = an * freq[f] * ((float)f * (PI_F / 32.0f));
  float emb = (lane < 32) ? __sinf(ph) : __cosf(ph);
  float h = b1[lane];
  const float* w1r = w1 + lane*64;
  #pragma unroll 8
  for (int i = 0; i < 64; ++i){
    float e = __shfl(emb, i, 64);
    h = fmaf(e, w1r[i], h);
  }
  float mu = wsum64(h) * (1.0f/64.0f);
  float d = h - mu;
  float var = wsum64(d*d) * (1.0f/64.0f);
  float hn = fmaf(d * rsqrtf(var + 1e-5f), lng[lane], lnb[lane]);
  float r = fmaxf(hn, 0.f);
  float o = b2[lane];
  const float* w2r = w2 + lane*64;
  #pragma unroll 8
  for (int i = 0; i < 64; ++i){
    float e = __shfl(r, i, 64);
    o = fmaf(e, w2r[i], o);
  }
  aemb[(size_t)p*64 + lane] = o;
}

// ---------------- 3/4) rotated deformable conv (3 hypotheses) ----------------
// block: 8 pixels x 256 output channels. LDS im2col [2304][8]. wt is K-major (2304,256).
__global__ __launch_bounds__(256, 2) void k_deform(const float* __restrict__ feat,
    const float* __restrict__ ang, const float* __restrict__ wt,
    const float* __restrict__ bias, float* __restrict__ cand){
  __shared__ float s[2304][8];
  int hyp = blockIdx.y;
  float delta = ((float)hyp - 1.0f) * (PI_F / 12.0f);
  int p0 = blockIdx.x * 8;
  int c = threadIdx.x;
  const float KYc[9] = {-1,-1,-1,0,0,0,1,1,1};
  const float KXc[9] = {-1,0,1,-1,0,1,-1,0,1};
  int b = p0 >> 12;
  int hw0 = p0 & 4095;
  int hh = hw0 >> 6, w0 = hw0 & 63;
  const float* fb = feat + (size_t)b*HWSZ*256 + c;
  #pragma unroll 1
  for (int pp = 0; pp < 8; ++pp){
    float a = ang[p0 + pp] + delta;
    float sn = __sinf(a), cs = __cosf(a);
    float fh = (float)hh, fw = (float)(w0 + pp);
    #pragma unroll
    for (int k = 0; k < 9; ++k){
      // py = h + rotated_tap_y ; px = w + rotated_tap_x  (offset-add cancels)
      float py = fh + KXc[k]*sn + KYc[k]*cs;
      float px = fw + KXc[k]*cs - KYc[k]*sn;
      float y0f = floorf(py), x0f = floorf(px);
      float wy = py - y0f, wx = px - x0f;
      int y0 = (int)y0f, x0 = (int)x0f;
      float v = 0.f;
      #pragma unroll
      for (int dy = 0; dy < 2; ++dy){
        int yy = y0 + dy;
        if (yy >= 0 && yy < 64){
          float fy = dy ? wy : 1.f - wy;
          #pragma unroll
          for (int dx = 0; dx < 2; ++dx){
            int xx = x0 + dx;
            if (xx >= 0 && xx < 64){
              float fx = dx ? wx : 1.f - wx;
              v = fmaf(fy*fx, fb[(size_t)(yy*64 + xx)*256], v);
            }
          }
        }
      }
      s[c*9 + k][pp] = v;
    }
  }
  __syncthreads();
  int o = c;
  float acc[8];
  float bo = bias[o];
  #pragma unroll
  for (int i = 0; i < 8; ++i) acc[i] = bo;
  const float* wp = wt + o;
  #pragma unroll 2
  for (int kk = 0; kk < 2304; ++kk){
    float wv = wp[(size_t)kk*256];
    const float4* row = reinterpret_cast<const float4*>(&s[kk][0]);
    float4 v0 = row[0], v1 = row[1];
    acc[0]=fmaf(v0.x,wv,acc[0]); acc[1]=fmaf(v0.y,wv,acc[1]);
    acc[2]=fmaf(v0.z,wv,acc[2]); acc[3]=fmaf(v0.w,wv,acc[3]);
    acc[4]=fmaf(v1.x,wv,acc[4]); acc[5]=fmaf(v1.y,wv,acc[5]);
    acc[6]=fmaf(v1.z,wv,acc[6]); acc[7]=fmaf(v1.w,wv,acc[7]);
  }
  float* op = cand + ((size_t)hyp*NPIX + p0)*256 + o;
  #pragma unroll
  for (int pp = 0; pp < 8; ++pp) op[(size_t)pp*256] = acc[pp];
}

// ---------------- 4) per-pixel MHA over 3 hypotheses (q = cand[1]) ----------------
__global__ void k_mha(const float* __restrict__ cand, const float* __restrict__ wt,
    const float* __restrict__ inb, const float* __restrict__ wot,
    const float* __restrict__ outb, float* __restrict__ fused){
  __shared__ float q[4][256];
  __shared__ float kv[4][3][256];
  __shared__ float osh[4][256];
  int p0 = blockIdx.x * 4;
  int j = threadIdx.x;
  #pragma unroll
  for (int pp = 0; pp < 4; ++pp){
    q[pp][j] = cand[((size_t)(NPIX + p0 + pp))*256 + j];
    #pragma unroll
    for (int i = 0; i < 3; ++i)
      kv[pp][i][j] = cand[((size_t)(i*NPIX + p0 + pp))*256 + j];
  }
  __syncthreads();
  float bq = inb[j], bk = inb[256+j], bv = inb[512+j];
  #pragma unroll 1
  for (int pp = 0; pp < 4; ++pp){
    float Q = bq;
    float K0 = bk, K1 = bk, K2 = bk;
    float V0 = bv, V1 = bv, V2 = bv;
    for (int e = 0; e < 256; ++e){
      const float* tp = wt + (size_t)e*768;
      float wq = tp[j], wk = tp[256+j], wv = tp[512+j];
      Q  = fmaf(q[pp][e],  wq, Q);
      float a0 = kv[pp][0][e], a1 = kv[pp][1][e], a2 = kv[pp][2][e];
      K0 = fmaf(a0, wk, K0); K1 = fmaf(a1, wk, K1); K2 = fmaf(a2, wk, K2);
      V0 = fmaf(a0, wv, V0); V1 = fmaf(a1, wv, V1); V2 = fmaf(a2, wv, V2);
    }
    const float sc = 0.17677669529663688f; // 1/sqrt(32)
    float s0 = wsum32(Q*K0) * sc;
    float s1 = wsum32(Q*K1) * sc;
    float s2 = wsum32(Q*K2) * sc;
    float m = fmaxf(s0, fmaxf(s1, s2));
    float e0 = __expf(s0-m), e1 = __expf(s1-m), e2 = __expf(s2-m);
    float inv = 1.f/(e0+e1+e2);
    osh[pp][j] = (e0*V0 + e1*V1 + e2*V2) * inv;
  }
  __syncthreads();
  #pragma unroll 1
  for (int pp = 0; pp < 4; ++pp){
    float o = outb[j];
    for (int e = 0; e < 256; ++e)
      o = fmaf(osh[pp][e], wot[(size_t)e*256 + j], o);
    fused[(size_t)(p0+pp)*256 + j] = o;
  }
}

// ---------------- 5) joint gate: enh = fused * (1 + sigmoid(mlp)) ----------------
__global__ void k_gate(const float* __restrict__ fused, const float* __restrict__ aemb,
    const float* __restrict__ w1t, const float* __restrict__ b1,
    const float* __restrict__ w2t, const float* __restrict__ b2,
    float* __restrict__ enh){
  __shared__ float f[4][256];
  __shared__ float ae[4][64];
  __shared__ float hid[4][256];
  int p0 = blockIdx.x * 4;
  int j = threadIdx.x;
  #pragma unroll
  for (int pp = 0; pp < 4; ++pp)
    f[pp][j] = fused[(size_t)(p0+pp)*256 + j];
  {
    int pp = j >> 6, e = j & 63;
    ae[pp][e] = aemb[(size_t)(p0+pp)*64 + e];
  }
  __syncthreads();
  #pragma unroll 1
  for (int pp = 0; pp < 4; ++pp){
    float h = b1[j];
    for (int e = 0; e < 256; ++e) h = fmaf(f[pp][e], w1t[(size_t)e*256 + j], h);
    #pragma unroll 4
    for (int e = 0; e < 64; ++e) h = fmaf(ae[pp][e], w1t[(size_t)(256+e)*256 + j], h);
    hid[pp][j] = fmaxf(h, 0.f);
  }
  __syncthreads();
  #pragma unroll 1
  for (int pp = 0; pp < 4; ++pp){
    float g = b2[j];
    for (int e = 0; e < 256; ++e) g = fmaf(hid[pp][e], w2t[(size_t)e*256 + j], g);
    float gate = 1.f/(1.f + __expf(-g));
    enh[(size_t)(p0+pp)*256 + j] = f[pp][j] * (1.f + gate);
  }
}

// ---------------- 6a) output 3x3 conv (same GEMM structure as deform) ----------------
__global__ __launch_bounds__(256, 2) void k_opconv(const float* __restrict__ enh,
    const float* __restrict__ wt, const float* __restrict__ bias, float* __restrict__ tout){
  __shared__ float s[2304][8];
  int p0 = blockIdx.x * 8;
  int c = threadIdx.x;
  int b = p0 >> 12;
  int hw0 = p0 & 4095;
  int hh = hw0 >> 6, w0 = hw0 & 63;
  const float* eb = enh + (size_t)b*HWSZ*256 + c;
  #pragma unroll 1
  for (int pp = 0; pp < 8; ++pp){
    int w = w0 + pp;
    #pragma unroll
    for (int ky = 0; ky < 3; ++ky){
      int y = hh + ky - 1;
      #pragma unroll
      for (int kx = 0; kx < 3; ++kx){
        int x = w + kx - 1;
        float v = (y >= 0 && y < 64 && x >= 0 && x < 64) ? eb[(size_t)(y*64 + x)*256] : 0.f;
        s[c*9 + ky*3 + kx][pp] = v;
      }
    }
  }
  __syncthreads();
  int o = c;
  float acc[8];
  float bo = bias[o];
  #pragma unroll
  for (int i = 0; i < 8; ++i) acc[i] = bo;
  const float* wp = wt + o;
  #pragma unroll 2
  for (int kk = 0; kk < 2304; ++kk){
    float wv = wp[(size_t)kk*256];
    const float4* row = reinterpret_cast<const float4*>(&s[kk][0]);
    float4 v0 = row[0], v1 = row[1];
    acc[0]=fmaf(v0.x,wv,acc[0]); acc[1]=fmaf(v0.y,wv,acc[1]);
    acc[2]=fmaf(v0.z,wv,acc[2]); acc[3]=fmaf(v0.w,wv,acc[3]);
    acc[4]=fmaf(v1.x,wv,acc[4]); acc[5]=fmaf(v1.y,wv,acc[5]);
    acc[6]=fmaf(v1.z,wv,acc[6]); acc[7]=fmaf(v1.w,wv,acc[7]);
  }
  float* op = tout + (size_t)p0*256 + o;
  #pragma unroll
  for (int pp = 0; pp < 8; ++pp) op[(size_t)pp*256] = acc[pp];
}

// ---------------- 6b) group-norm stats (32 groups of 8 channels) ----------------
__global__ void k_gnstat(const float* __restrict__ t, float* __restrict__ stat){
  int bg = blockIdx.x;
  int b = bg >> 5, g = bg & 31;
  const float* base = t + (size_t)b*HWSZ*256 + g*8;
  float s = 0.f, s2 = 0.f;
  for (int idx = threadIdx.x; idx < 8*HWSZ; idx += 256){
    int p = idx >> 3, cc = idx & 7;
    float v = base[(size_t)p*256 + cc];
    s += v; s2 = fmaf(v, v, s2);
  }
  s = wsum64(s); s2 = wsum64(s2);
  __shared__ float rs[4], rs2[4];
  int wid = threadIdx.x >> 6;
  if ((threadIdx.x & 63) == 0){ rs[wid] = s; rs2[wid] = s2; }
  __syncthreads();
  if (threadIdx.x == 0){
    float S = rs[0]+rs[1]+rs[2]+rs[3];
    float S2 = rs2[0]+rs2[1]+rs2[2]+rs2[3];
    float mean = S * (1.f/32768.f);
    float var = S2 * (1.f/32768.f) - mean*mean;
    stat[bg*2]   = mean;
    stat[bg*2+1] = rsqrtf(var + 1e-5f);
  }
}

// ---------------- 6c) fused GN+relu + 1x1 conv, NCHW output ----------------
__global__ void k_final(const float* __restrict__ t, const float* __restrict__ stat,
    const float* __restrict__ gng, const float* __restrict__ gnb,
    const float* __restrict__ w2t, const float* __restrict__ b2,
    float* __restrict__ out){
  __shared__ float a[256][8];
  __shared__ float os[256][8];
  int p0 = blockIdx.x * 8;
  int c = threadIdx.x;
  int b = p0 >> 12;
  int g = c >> 3;
  float mean = stat[(b*32+g)*2], rstd = stat[(b*32+g)*2+1];
  float gg = gng[c] * rstd;
  float bb = gnb[c] - mean*gg;
  #pragma unroll
  for (int pp = 0; pp < 8; ++pp){
    float v = t[(size_t)(p0+pp)*256 + c];
    a[c][pp] = fmaxf(fmaf(v, gg, bb), 0.f);
  }
  __syncthreads();
  float acc[8];
  float bo = b2[c];
  #pragma unroll
  for (int i = 0; i < 8; ++i) acc[i] = bo;
  const float* wp = w2t + c;
  #pragma unroll 2
  for (int cc = 0; cc < 256; ++cc){
    float wv = wp[(size_t)cc*256];
    const float4* row = reinterpret_cast<const float4*>(&a[cc][0]);
    float4 v0 = row[0], v1 = row[1];
    acc[0]=fmaf(v0.x,wv,acc[0]); acc[1]=fmaf(v0.y,wv,acc[1]);
    acc[2]=fmaf(v0.z,wv,acc[2]); acc[3]=fmaf(v0.w,wv,acc[3]);
    acc[4]=fmaf(v1.x,wv,acc[4]); acc[5]=fmaf(v1.y,wv,acc[5]);
    acc[6]=fmaf(v1.z,wv,acc[6]); acc[7]=fmaf(v1.w,wv,acc[7]);
  }
  #pragma unroll
  for (int pp = 0; pp < 8; ++pp) os[c][pp] = acc[pp];
  __syncthreads();
  int hh = (p0 & 4095) >> 6, w0 = p0 & 63;
  #pragma unroll
  for (int i = 0; i < 8; ++i){
    int flat = i*256 + (int)threadIdx.x;
    int o2 = flat >> 3, pp = flat & 7;
    out[((size_t)(b*256 + o2)*64 + hh)*64 + w0 + pp] = os[o2][pp];
  }
}

// ---------------- launch ----------------
extern "C" void kernel_launch(void* const* d_in, const int* in_sizes, int n_in,
                              void* d_out, int out_size, void* d_ws, size_t ws_size,
                              hipStream_t stream){
  (void)in_sizes; (void)n_in; (void)out_size; (void)ws_size;
  const float* features   = (const float*)d_in[0];
  const float* ap_w1      = (const float*)d_in[1];
  const float* ap_b1      = (const float*)d_in[2];
  const float* ap_w2      = (const float*)d_in[3];
  const float* ap_b2      = (const float*)d_in[4];
  const float* freq       = (const float*)d_in[5];
  const float* ae_w1      = (const float*)d_in[6];
  const float* ae_b1      = (const float*)d_in[7];
  const float* ae_ln_g    = (const float*)d_in[8];
  const float* ae_ln_b    = (const float*)d_in[9];
  const float* ae_w2      = (const float*)d_in[10];
  const float* ae_b2      = (const float*)d_in[11];
  const float* dc_w       = (const float*)d_in[12];
  const float* dc_b       = (const float*)d_in[13];
  const float* attn_in_w  = (const float*)d_in[14];
  const float* attn_in_b  = (const float*)d_in[15];
  const float* attn_out_w = (const float*)d_in[16];
  const float* attn_out_b = (const float*)d_in[17];
  const float* ja_w1      = (const float*)d_in[18];
  const float* ja_b1      = (const float*)d_in[19];
  const float* ja_w2      = (const float*)d_in[20];
  const float* ja_b2      = (const float*)d_in[21];
  const float* op_w1      = (const float*)d_in[22];
  const float* op_b1      = (const float*)d_in[23];
  const float* gn_g       = (const float*)d_in[24];
  const float* gn_b       = (const float*)d_in[25];
  const float* op_w2      = (const float*)d_in[26];
  const float* op_b2      = (const float*)d_in[27];

  float* ws = (float*)d_ws;
  float* feat_nhwc = ws;  ws += 2097152;
  float* h1buf     = ws;  ws += 524288;
  float* angbuf    = ws;  ws += 8192;
  float* aembbuf   = ws;  ws += 524288;
  float* wdct      = ws;  ws += 589824;
  float* wint      = ws;  ws += 196608;
  float* wott      = ws;  ws += 65536;
  float* jw1t      = ws;  ws += 81920;
  float* jw2t      = ws;  ws += 65536;
  float* wop1t     = ws;  ws += 589824;
  float* wop2t     = ws;  ws += 65536;
  float* candbuf   = ws;  ws += 6291456;
  float* fusedbuf  = ws;  ws += 2097152;
  float* enhbuf    = ws;  ws += 2097152;
  float* tbuf      = ws;  ws += 2097152;
  float* gstat     = ws;  ws += 128;

  dim3 t32(32, 8);
  k_nchw_to_nhwc<<<dim3(128,8,2), t32, 0, stream>>>(features, feat_nhwc);
  k_transpose<<<dim3(72,8),  t32, 0, stream>>>(dc_w,       wdct,  256, 2304);
  k_transpose<<<dim3(8,24),  t32, 0, stream>>>(attn_in_w,  wint,  768, 256);
  k_transpose<<<dim3(8,8),   t32, 0, stream>>>(attn_out_w, wott,  256, 256);
  k_transpose<<<dim3(10,8),  t32, 0, stream>>>(ja_w1,      jw1t,  256, 320);
  k_transpose<<<dim3(8,8),   t32, 0, stream>>>(ja_w2,      jw2t,  256, 256);
  k_transpose<<<dim3(72,8),  t32, 0, stream>>>(op_w1,      wop1t, 256, 2304);
  k_transpose<<<dim3(8,8),   t32, 0, stream>>>(op_w2,      wop2t, 256, 256);

  k_apconv1<<<dim3(64,16,2), 256, 0, stream>>>(features, ap_w1, ap_b1, h1buf);
  k_angles<<<32, 256, 0, stream>>>(h1buf, ap_w2, ap_b2, angbuf);
  k_angle_encode<<<2048, 256, 0, stream>>>(angbuf, freq, ae_w1, ae_b1, ae_ln_g, ae_ln_b,
                                           ae_w2, ae_b2, aembbuf);
  k_deform<<<dim3(1024,3), 256, 0, stream>>>(feat_nhwc, angbuf, wdct, dc_b, candbuf);
  k_mha<<<2048, 256, 0, stream>>>(candbuf, wint, attn_in_b, wott, attn_out_b, fusedbuf);
  k_gate<<<2048, 256, 0, stream>>>(fusedbuf, aembbuf, jw1t, ja_b1, jw2t, ja_b2, enhbuf);
  k_opconv<<<1024, 256, 0, stream>>>(enhbuf, wop1t, op_b1, tbuf);
  k_gnstat<<<64, 256, 0, stream>>>(tbuf, gstat);
  k_final<<<1024, 256, 0, stream>>>(tbuf, gstat, gn_g, gn_b, wop2t, op_b2, (float*)d_out);
}

// Round 2
// 1212.849 us; speedup vs baseline: 2.1311x; 2.1311x over previous
//
#include <hip/hip_runtime.h>

#define PI_F 3.14159265358979323846f
#define HWSZ 4096   // H*W
#define NPIX 8192   // B*H*W

typedef __attribute__((ext_vector_type(8))) short short8;
typedef __attribute__((ext_vector_type(4))) float f32x4;

__device__ __forceinline__ short f2bf(float x){
  unsigned u = __float_as_uint(x);
  unsigned r = (u + 0x7FFFu + ((u >> 16) & 1u)) >> 16;
  return (short)r;
}
__device__ __forceinline__ float bf2f(short v){
  return __uint_as_float(((unsigned)(unsigned short)v) << 16);
}

// ---------------- wave reductions ----------------
__device__ __forceinline__ float wsum64(float v){
  #pragma unroll
  for (int m = 32; m >= 1; m >>= 1) v += __shfl_xor(v, m, 64);
  return v;
}
__device__ __forceinline__ float wsum32(float v){
  #pragma unroll
  for (int m = 16; m >= 1; m >>= 1) v += __shfl_xor(v, m, 64);
  return v;
}

// ---------------- layout transforms ----------------
// features (B,256,H,W) -> bf16 (B,H,W,256)
__global__ void k_nchw_to_nhwc_bf(const float* __restrict__ in, short* __restrict__ out){
  __shared__ float tile[32][33];
  int b = blockIdx.z;
  int p0 = blockIdx.x * 32, c0 = blockIdx.y * 32;
  int tx = threadIdx.x, ty = threadIdx.y;
  #pragma unroll
  for (int i = ty; i < 32; i += 8)
    tile[i][tx] = in[((size_t)b*256 + c0 + i)*HWSZ + p0 + tx];
  __syncthreads();
  #pragma unroll
  for (int i = ty; i < 32; i += 8)
    out[((size_t)b*HWSZ + p0 + i)*256 + c0 + tx] = f2bf(tile[tx][i]);
}

// generic fp32 2D transpose: in (R,Cn) -> out (Cn,R). R,Cn multiples of 32.
__global__ void k_transpose(const float* __restrict__ in, float* __restrict__ out, int R, int Cn){
  __shared__ float tile[32][33];
  int r0 = blockIdx.y * 32, c0 = blockIdx.x * 32;
  int tx = threadIdx.x, ty = threadIdx.y;
  #pragma unroll
  for (int i = ty; i < 32; i += 8)
    tile[i][tx] = in[(size_t)(r0 + i)*Cn + c0 + tx];
  __syncthreads();
  #pragma unroll
  for (int i = ty; i < 32; i += 8)
    out[(size_t)(c0 + i)*R + r0 + tx] = tile[tx][i];
}

// 3x3 conv weight (O=256, C=256, 9) -> bf16 B[n=k*256+o][c=0..255]
__global__ void k_prep_tapw(const float* __restrict__ w, short* __restrict__ Bm){
  int n = blockIdx.x, c = threadIdx.x;
  int k = n >> 8, o = n & 255;
  Bm[(size_t)n*256 + c] = f2bf(w[((size_t)o*256 + c)*9 + k]);
}

// ---------------- bf16 TN GEMM: C[M][N] = A[M][K] x B[N][K]^T, bf16 out ----------------
// block 256 thr = 4 waves (2x2), wave tile 32x64 via 16x16x32 MFMA. No LDS.
__global__ __launch_bounds__(256) void k_gemm_tn_bf16(
    const short* __restrict__ A, const short* __restrict__ Bm,
    short* __restrict__ C, int M, int N, int K){
  int w = threadIdx.x >> 6, l = threadIdx.x & 63;
  int m0 = blockIdx.x*64 + (w & 1)*32;
  int n0 = blockIdx.y*128 + (w >> 1)*64;
  int ml = l & 15, g = l >> 4;
  f32x4 acc[2][4];
  #pragma unroll
  for (int i = 0; i < 2; ++i)
    #pragma unroll
    for (int j = 0; j < 4; ++j) acc[i][j] = (f32x4){0.f,0.f,0.f,0.f};
  const short* Ap = A + (size_t)(m0 + ml)*K + g*8;
  const short* Bp = Bm + (size_t)(n0 + ml)*K + g*8;
  for (int k0 = 0; k0 < K; k0 += 32){
    short8 a0 = *(const short8*)(Ap + k0);
    short8 a1 = *(const short8*)(Ap + (size_t)16*K + k0);
    short8 b0 = *(const short8*)(Bp + k0);
    short8 b1 = *(const short8*)(Bp + (size_t)16*K + k0);
    short8 b2 = *(const short8*)(Bp + (size_t)32*K + k0);
    short8 b3 = *(const short8*)(Bp + (size_t)48*K + k0);
    acc[0][0] = __builtin_amdgcn_mfma_f32_16x16x32_bf16(a0, b0, acc[0][0], 0, 0, 0);
    acc[0][1] = __builtin_amdgcn_mfma_f32_16x16x32_bf16(a0, b1, acc[0][1], 0, 0, 0);
    acc[0][2] = __builtin_amdgcn_mfma_f32_16x16x32_bf16(a0, b2, acc[0][2], 0, 0, 0);
    acc[0][3] = __builtin_amdgcn_mfma_f32_16x16x32_bf16(a0, b3, acc[0][3], 0, 0, 0);
    acc[1][0] = __builtin_amdgcn_mfma_f32_16x16x32_bf16(a1, b0, acc[1][0], 0, 0, 0);
    acc[1][1] = __builtin_amdgcn_mfma_f32_16x16x32_bf16(a1, b1, acc[1][1], 0, 0, 0);
    acc[1][2] = __builtin_amdgcn_mfma_f32_16x16x32_bf16(a1, b2, acc[1][2], 0, 0, 0);
    acc[1][3] = __builtin_amdgcn_mfma_f32_16x16x32_bf16(a1, b3, acc[1][3], 0, 0, 0);
  }
  #pragma unroll
  for (int fm = 0; fm < 2; ++fm)
    #pragma unroll
    for (int fn = 0; fn < 4; ++fn)
      #pragma unroll
      for (int r = 0; r < 4; ++r){
        int row = m0 + fm*16 + g*4 + r;
        int col = n0 + fn*16 + ml;
        C[(size_t)row*N + col] = f2bf(acc[fm][fn][r]);
      }
}

// ---------------- 1) angle prediction ----------------
__global__ void k_apconv1(const float* __restrict__ feat, const float* __restrict__ w1,
    const float* __restrict__ b1, float* __restrict__ h1){
  int w = threadIdx.x & 63, oi = threadIdx.x >> 6;
  int h = blockIdx.x, o = blockIdx.y*4 + oi, b = blockIdx.z;
  float acc = b1[o];
  const float* wp = w1 + (size_t)o*256*9;
  const float* fpb = feat + (size_t)b*256*HWSZ;
  for (int c = 0; c < 256; ++c){
    const float* fc = fpb + (size_t)c*HWSZ;
    const float* wc = wp + c*9;
    #pragma unroll
    for (int ky = 0; ky < 3; ++ky){
      int y = h + ky - 1;
      if (y < 0 || y > 63) continue;
      const float* fr = fc + y*64;
      #pragma unroll
      for (int kx = 0; kx < 3; ++kx){
        int x = w + kx - 1;
        if (x >= 0 && x < 64)
          acc = fmaf(fr[x], wc[ky*3+kx], acc);
      }
    }
  }
  h1[((size_t)(b*64 + o)*64 + h)*64 + w] = fmaxf(acc, 0.f);
}

__global__ void k_angles(const float* __restrict__ h1, const float* __restrict__ w2,
    const float* __restrict__ b2, float* __restrict__ ang){
  int p = blockIdx.x*256 + threadIdx.x;
  int b = p >> 12, hw = p & 4095;
  float acc = b2[0];
  const float* hb = h1 + (size_t)b*64*HWSZ + hw;
  #pragma unroll 8
  for (int c = 0; c < 64; ++c)
    acc = fmaf(hb[(size_t)c*HWSZ], w2[c], acc);
  ang[p] = acc;
}

// ---------------- 2) angle encoding ----------------
__global__ void k_angle_encode(const float* __restrict__ ang, const float* __restrict__ freq,
    const float* __restrict__ w1, const float* __restrict__ b1,
    const float* __restrict__ lng, const float* __restrict__ lnb,
    const float* __restrict__ w2, const float* __restrict__ b2,
    float* __restrict__ aemb){
  int lane = threadIdx.x & 63;
  int p = blockIdx.x * 4 + (threadIdx.x >> 6);
  float an = ang[p] * (2.0f / PI_F);
  int f = lane & 31;
  float ph = an * freq[f] * ((float)f * (PI_F / 32.0f));
  float emb = (lane < 32) ? __sinf(ph) : __cosf(ph);
  float h = b1[lane];
  const float* w1r = w1 + lane*64;
  #pragma unroll 8
  for (int i = 0; i < 64; ++i){
    float e = __shfl(emb, i, 64);
    h = fmaf(e, w1r[i], h);
  }
  float mu = wsum64(h) * (1.0f/64.0f);
  float d = h - mu;
  float var = wsum64(d*d) * (1.0f/64.0f);
  float hn = fmaf(d * rsqrtf(var + 1e-5f), lng[lane], lnb[lane]);
  float r = fmaxf(hn, 0.f);
  float o = b2[lane];
  const float* w2r = w2 + lane*64;
  #pragma unroll 8
  for (int i = 0; i < 64; ++i){
    float e = __shfl(r, i, 64);
    o = fmaf(e, w2r[i], o);
  }
  aemb[(size_t)p*64 + lane] = o;
}

// ---------------- 3/4) bilinear gather on tap-features G ----------------
// G bf16 [pix=8192][k*256+o]; cand[hyp][p][o] = dc_b[o] + sum_k bilin(G_k, pos)
__global__ void k_sample(const short* __restrict__ G, const float* __restrict__ ang,
    const float* __restrict__ bias, float* __restrict__ cand){
  const float KYc[9] = {-1,-1,-1,0,0,0,1,1,1};
  const float KXc[9] = {-1,0,1,-1,0,1,-1,0,1};
  int p = blockIdx.x, hyp = blockIdx.y, o = threadIdx.x;
  float a = ang[p] + ((float)hyp - 1.0f) * (PI_F / 12.0f);
  float sn = __sinf(a), cs = __cosf(a);
  int b = p >> 12, hw = p & 4095;
  int h = hw >> 6, w = hw & 63;
  float fh = (float)h, fw = (float)w;
  float acc = bias[o];
  #pragma unroll
  for (int k = 0; k < 9; ++k){
    float py = fh + KXc[k]*sn + KYc[k]*cs;
    float px = fw + KXc[k]*cs - KYc[k]*sn;
    float y0f = floorf(py), x0f = floorf(px);
    float wy = py - y0f, wx = px - x0f;
    int y0 = (int)y0f, x0 = (int)x0f;
    const short* Gk = G + k*256 + o;
    #pragma unroll
    for (int dy = 0; dy < 2; ++dy){
      int yy = y0 + dy;
      if (yy < 0 || yy > 63) continue;
      float fy = dy ? wy : 1.f - wy;
      #pragma unroll
      for (int dx = 0; dx < 2; ++dx){
        int xx = x0 + dx;
        if (xx < 0 || xx > 63) continue;
        float fx = dx ? wx : 1.f - wx;
        acc = fmaf(fy*fx, bf2f(Gk[(size_t)(b*HWSZ + yy*64 + xx)*2304]), acc);
      }
    }
  }
  cand[((size_t)hyp*NPIX + p)*256 + o] = acc;
}

// ---------------- 4) per-pixel MHA over 3 hypotheses (q = cand[1]) ----------------
__global__ void k_mha(const float* __restrict__ cand, const float* __restrict__ wt,
    const float* __restrict__ inb, const float* __restrict__ wot,
    const float* __restrict__ outb, float* __restrict__ fused){
  __shared__ float q[4][256];
  __shared__ float kv[4][3][256];
  __shared__ float osh[4][256];
  int p0 = blockIdx.x * 4;
  int j = threadIdx.x;
  #pragma unroll
  for (int pp = 0; pp < 4; ++pp){
    q[pp][j] = cand[((size_t)(NPIX + p0 + pp))*256 + j];
    #pragma unroll
    for (int i = 0; i < 3; ++i)
      kv[pp][i][j] = cand[((size_t)(i*NPIX + p0 + pp))*256 + j];
  }
  __syncthreads();
  float bq = inb[j], bk = inb[256+j], bv = inb[512+j];
  #pragma unroll 1
  for (int pp = 0; pp < 4; ++pp){
    float Q = bq;
    float K0 = bk, K1 = bk, K2 = bk;
    float V0 = bv, V1 = bv, V2 = bv;
    for (int e = 0; e < 256; ++e){
      const float* tp = wt + (size_t)e*768;
      float wq = tp[j], wk = tp[256+j], wv = tp[512+j];
      Q  = fmaf(q[pp][e],  wq, Q);
      float a0 = kv[pp][0][e], a1 = kv[pp][1][e], a2 = kv[pp][2][e];
      K0 = fmaf(a0, wk, K0); K1 = fmaf(a1, wk, K1); K2 = fmaf(a2, wk, K2);
      V0 = fmaf(a0, wv, V0); V1 = fmaf(a1, wv, V1); V2 = fmaf(a2, wv, V2);
    }
    const float sc = 0.17677669529663688f; // 1/sqrt(32)
    float s0 = wsum32(Q*K0) * sc;
    float s1 = wsum32(Q*K1) * sc;
    float s2 = wsum32(Q*K2) * sc;
    float m = fmaxf(s0, fmaxf(s1, s2));
    float e0 = __expf(s0-m), e1 = __expf(s1-m), e2 = __expf(s2-m);
    float inv = 1.f/(e0+e1+e2);
    osh[pp][j] = (e0*V0 + e1*V1 + e2*V2) * inv;
  }
  __syncthreads();
  #pragma unroll 1
  for (int pp = 0; pp < 4; ++pp){
    float o = outb[j];
    for (int e = 0; e < 256; ++e)
      o = fmaf(osh[pp][e], wot[(size_t)e*256 + j], o);
    fused[(size_t)(p0+pp)*256 + j] = o;
  }
}

// ---------------- 5) joint gate: enh = fused * (1 + sigmoid(mlp)), bf16 out ----------------
__global__ void k_gate(const float* __restrict__ fused, const float* __restrict__ aemb,
    const float* __restrict__ w1t, const float* __restrict__ b1,
    const float* __restrict__ w2t, const float* __restrict__ b2,
    short* __restrict__ enh){
  __shared__ float f[4][256];
  __shared__ float ae[4][64];
  __shared__ float hid[4][256];
  int p0 = blockIdx.x * 4;
  int j = threadIdx.x;
  #pragma unroll
  for (int pp = 0; pp < 4; ++pp)
    f[pp][j] = fused[(size_t)(p0+pp)*256 + j];
  {
    int pp = j >> 6, e = j & 63;
    ae[pp][e] = aemb[(size_t)(p0+pp)*64 + e];
  }
  __syncthreads();
  #pragma unroll 1
  for (int pp = 0; pp < 4; ++pp){
    float h = b1[j];
    for (int e = 0; e < 256; ++e) h = fmaf(f[pp][e], w1t[(size_t)e*256 + j], h);
    #pragma unroll 4
    for (int e = 0; e < 64; ++e) h = fmaf(ae[pp][e], w1t[(size_t)(256+e)*256 + j], h);
    hid[pp][j] = fmaxf(h, 0.f);
  }
  __syncthreads();
  #pragma unroll 1
  for (int pp = 0; pp < 4; ++pp){
    float g = b2[j];
    for (int e = 0; e < 256; ++e) g = fmaf(hid[pp][e], w2t[(size_t)e*256 + j], g);
    float gate = 1.f/(1.f + __expf(-g));
    enh[(size_t)(p0+pp)*256 + j] = f2bf(f[pp][j] * (1.f + gate));
  }
}

// ---------------- 6a2) shift-add of tap conv outputs H -> t (fp32) ----------------
__global__ void k_shiftadd(const short* __restrict__ Hm, const float* __restrict__ b1,
    float* __restrict__ t){
  const int KYi[9] = {-1,-1,-1,0,0,0,1,1,1};
  const int KXi[9] = {-1,0,1,-1,0,1,-1,0,1};
  int p = blockIdx.x, o = threadIdx.x;
  int b = p >> 12, hw = p & 4095;
  int h = hw >> 6, w = hw & 63;
  float acc = b1[o];
  #pragma unroll
  for (int k = 0; k < 9; ++k){
    int y = h + KYi[k], x = w + KXi[k];
    if (y < 0 || y > 63 || x < 0 || x > 63) continue;
    acc += bf2f(Hm[(size_t)(b*HWSZ + y*64 + x)*2304 + k*256 + o]);
  }
  t[(size_t)p*256 + o] = acc;
}

// ---------------- 6b) group-norm stats ----------------
__global__ void k_gnstat(const float* __restrict__ t, float* __restrict__ stat){
  int bg = blockIdx.x;
  int b = bg >> 5, g = bg & 31;
  const float* base = t + (size_t)b*HWSZ*256 + g*8;
  float s = 0.f, s2 = 0.f;
  for (int idx = threadIdx.x; idx < 8*HWSZ; idx += 256){
    int p = idx >> 3, cc = idx & 7;
    float v = base[(size_t)p*256 + cc];
    s += v; s2 = fmaf(v, v, s2);
  }
  s = wsum64(s); s2 = wsum64(s2);
  __shared__ float rs[4], rs2[4];
  int wid = threadIdx.x >> 6;
  if ((threadIdx.x & 63) == 0){ rs[wid] = s; rs2[wid] = s2; }
  __syncthreads();
  if (threadIdx.x == 0){
    float S = rs[0]+rs[1]+rs[2]+rs[3];
    float S2 = rs2[0]+rs2[1]+rs2[2]+rs2[3];
    float mean = S * (1.f/32768.f);
    float var = S2 * (1.f/32768.f) - mean*mean;
    stat[bg*2]   = mean;
    stat[bg*2+1] = rsqrtf(var + 1e-5f);
  }
}

// ---------------- 6c) fused GN+relu + 1x1 conv, NCHW output ----------------
__global__ void k_final(const float* __restrict__ t, const float* __restrict__ stat,
    const float* __restrict__ gng, const float* __restrict__ gnb,
    const float* __restrict__ w2t, const float* __restrict__ b2,
    float* __restrict__ out){
  __shared__ float a[256][8];
  __shared__ float os[256][8];
  int p0 = blockIdx.x * 8;
  int c = threadIdx.x;
  int b = p0 >> 12;
  int g = c >> 3;
  float mean = stat[(b*32+g)*2], rstd = stat[(b*32+g)*2+1];
  float gg = gng[c] * rstd;
  float bb = gnb[c] - mean*gg;
  #pragma unroll
  for (int pp = 0; pp < 8; ++pp){
    float v = t[(size_t)(p0+pp)*256 + c];
    a[c][pp] = fmaxf(fmaf(v, gg, bb), 0.f);
  }
  __syncthreads();
  float acc[8];
  float bo = b2[c];
  #pragma unroll
  for (int i = 0; i < 8; ++i) acc[i] = bo;
  const float* wp = w2t + c;
  #pragma unroll 2
  for (int cc = 0; cc < 256; ++cc){
    float wv = wp[(size_t)cc*256];
    const float4* row = reinterpret_cast<const float4*>(&a[cc][0]);
    float4 v0 = row[0], v1 = row[1];
    acc[0]=fmaf(v0.x,wv,acc[0]); acc[1]=fmaf(v0.y,wv,acc[1]);
    acc[2]=fmaf(v0.z,wv,acc[2]); acc[3]=fmaf(v0.w,wv,acc[3]);
    acc[4]=fmaf(v1.x,wv,acc[4]); acc[5]=fmaf(v1.y,wv,acc[5]);
    acc[6]=fmaf(v1.z,wv,acc[6]); acc[7]=fmaf(v1.w,wv,acc[7]);
  }
  #pragma unroll
  for (int pp = 0; pp < 8; ++pp) os[c][pp] = acc[pp];
  __syncthreads();
  int hh = (p0 & 4095) >> 6, w0 = p0 & 63;
  #pragma unroll
  for (int i = 0; i < 8; ++i){
    int flat = i*256 + (int)threadIdx.x;
    int o2 = flat >> 3, pp = flat & 7;
    out[((size_t)(b*256 + o2)*64 + hh)*64 + w0 + pp] = os[o2][pp];
  }
}

// ---------------- launch ----------------
extern "C" void kernel_launch(void* const* d_in, const int* in_sizes, int n_in,
                              void* d_out, int out_size, void* d_ws, size_t ws_size,
                              hipStream_t stream){
  (void)in_sizes; (void)n_in; (void)out_size; (void)ws_size;
  const float* features   = (const float*)d_in[0];
  const float* ap_w1      = (const float*)d_in[1];
  const float* ap_b1      = (const float*)d_in[2];
  const float* ap_w2      = (const float*)d_in[3];
  const float* ap_b2      = (const float*)d_in[4];
  const float* freq       = (const float*)d_in[5];
  const float* ae_w1      = (const float*)d_in[6];
  const float* ae_b1      = (const float*)d_in[7];
  const float* ae_ln_g    = (const float*)d_in[8];
  const float* ae_ln_b    = (const float*)d_in[9];
  const float* ae_w2      = (const float*)d_in[10];
  const float* ae_b2      = (const float*)d_in[11];
  const float* dc_w       = (const float*)d_in[12];
  const float* dc_b       = (const float*)d_in[13];
  const float* attn_in_w  = (const float*)d_in[14];
  const float* attn_in_b  = (const float*)d_in[15];
  const float* attn_out_w = (const float*)d_in[16];
  const float* attn_out_b = (const float*)d_in[17];
  const float* ja_w1      = (const float*)d_in[18];
  const float* ja_b1      = (const float*)d_in[19];
  const float* ja_w2      = (const float*)d_in[20];
  const float* ja_b2      = (const float*)d_in[21];
  const float* op_w1      = (const float*)d_in[22];
  const float* op_b1      = (const float*)d_in[23];
  const float* gn_g       = (const float*)d_in[24];
  const float* gn_b       = (const float*)d_in[25];
  const float* op_w2      = (const float*)d_in[26];
  const float* op_b2      = (const float*)d_in[27];

  float* ws = (float*)d_ws;
  float* wint    = ws;  ws += 196608;   // attn_in_w^T (256,768)
  float* wott    = ws;  ws += 65536;    // attn_out_w^T
  float* jw1t    = ws;  ws += 81920;    // ja_w1^T (320,256)
  float* jw2t    = ws;  ws += 65536;    // ja_w2^T
  float* wop2t   = ws;  ws += 65536;    // op_w2^T
  float* angbuf  = ws;  ws += 8192;
  float* aembbuf = ws;  ws += 524288;
  short* feat_bf = (short*)ws; ws += 1048576;   // 8192x256 bf16
  short* Bdc     = (short*)ws; ws += 294912;    // 2304x256 bf16
  short* Bop     = (short*)ws; ws += 294912;    // 2304x256 bf16
  float* candbuf = ws;  ws += 6291456;  // 3x8192x256 fp32
  float* fusedbuf= ws;  ws += 2097152;
  short* enh_bf  = (short*)ws; ws += 1048576;   // 8192x256 bf16
  float* tbuf    = ws;  ws += 2097152;
  float* gstat   = ws;  ws += 128;
  float* Greg    = ws;  ws += 9437184;  // 8192x2304 bf16 (G, later H)
  short* Gbuf    = (short*)Greg;
  float* h1buf   = Greg;                // alias: h1 dead before G written

  dim3 t32(32, 8);
  k_nchw_to_nhwc_bf<<<dim3(128,8,2), t32, 0, stream>>>(features, feat_bf);
  k_transpose<<<dim3(8,24),  t32, 0, stream>>>(attn_in_w,  wint,  768, 256);
  k_transpose<<<dim3(8,8),   t32, 0, stream>>>(attn_out_w, wott,  256, 256);
  k_transpose<<<dim3(10,8),  t32, 0, stream>>>(ja_w1,      jw1t,  256, 320);
  k_transpose<<<dim3(8,8),   t32, 0, stream>>>(ja_w2,      jw2t,  256, 256);
  k_transpose<<<dim3(8,8),   t32, 0, stream>>>(op_w2,      wop2t, 256, 256);
  k_prep_tapw<<<2304, 256, 0, stream>>>(dc_w,  Bdc);
  k_prep_tapw<<<2304, 256, 0, stream>>>(op_w1, Bop);

  k_apconv1<<<dim3(64,16,2), 256, 0, stream>>>(features, ap_w1, ap_b1, h1buf);
  k_angles<<<32, 256, 0, stream>>>(h1buf, ap_w2, ap_b2, angbuf);
  k_angle_encode<<<2048, 256, 0, stream>>>(angbuf, freq, ae_w1, ae_b1, ae_ln_g, ae_ln_b,
                                           ae_w2, ae_b2, aembbuf);
  // G = feat x Bdc^T : (8192,2304)
  k_gemm_tn_bf16<<<dim3(128,18), 256, 0, stream>>>(feat_bf, Bdc, Gbuf, NPIX, 2304, 256);
  k_sample<<<dim3(NPIX,3), 256, 0, stream>>>(Gbuf, angbuf, dc_b, candbuf);
  k_mha<<<2048, 256, 0, stream>>>(candbuf, wint, attn_in_b, wott, attn_out_b, fusedbuf);
  k_gate<<<2048, 256, 0, stream>>>(fusedbuf, aembbuf, jw1t, ja_b1, jw2t, ja_b2, enh_bf);
  // H = enh x Bop^T : (8192,2304)  (aliases G region; G is dead)
  k_gemm_tn_bf16<<<dim3(128,18), 256, 0, stream>>>(enh_bf, Bop, Gbuf, NPIX, 2304, 256);
  k_shiftadd<<<NPIX, 256, 0, stream>>>(Gbuf, op_b1, tbuf);
  k_gnstat<<<64, 256, 0, stream>>>(tbuf, gstat);
  k_final<<<1024, 256, 0, stream>>>(tbuf, gstat, gn_g, gn_b, wop2t, op_b2, (float*)d_out);
}

// Round 3
// 531.283 us; speedup vs baseline: 4.8650x; 2.2829x over previous
//
#include <hip/hip_runtime.h>

#define PI_F 3.14159265358979323846f
#define HWSZ 4096   // H*W
#define NPIX 8192   // B*H*W

typedef __attribute__((ext_vector_type(8))) short short8;
typedef __attribute__((ext_vector_type(4))) short short4_t;
typedef __attribute__((ext_vector_type(4))) float f32x4;

__device__ __forceinline__ short f2bf(float x){
  unsigned u = __float_as_uint(x);
  unsigned r = (u + 0x7FFFu + ((u >> 16) & 1u)) >> 16;
  return (short)r;
}
__device__ __forceinline__ float bf2f(short v){
  return __uint_as_float(((unsigned)(unsigned short)v) << 16);
}

__device__ __forceinline__ float wsum64(float v){
  #pragma unroll
  for (int m = 32; m >= 1; m >>= 1) v += __shfl_xor(v, m, 64);
  return v;
}
__device__ __forceinline__ float wsum8(float v){
  v += __shfl_xor(v, 1, 64);
  v += __shfl_xor(v, 2, 64);
  v += __shfl_xor(v, 4, 64);
  return v;
}

// ---------------- prep kernels ----------------
// features (B,256,H,W) -> feat_bf (B,H,W,256) hi ; A3 (p,768)=[hi|hi|lo]
__global__ void k_nchw_split(const float* __restrict__ in, short* __restrict__ feat_bf,
    short* __restrict__ A3){
  __shared__ float tile[32][33];
  int b = blockIdx.z;
  int p0 = blockIdx.x * 32, c0 = blockIdx.y * 32;
  int tx = threadIdx.x, ty = threadIdx.y;
  #pragma unroll
  for (int i = ty; i < 32; i += 8)
    tile[i][tx] = in[((size_t)b*256 + c0 + i)*HWSZ + p0 + tx];
  __syncthreads();
  #pragma unroll
  for (int i = ty; i < 32; i += 8){
    float x = tile[tx][i];
    short hi = f2bf(x);
    short lo = f2bf(x - bf2f(hi));
    size_t p = (size_t)b*HWSZ + p0 + i;
    feat_bf[p*256 + c0 + tx] = hi;
    A3[p*768 + c0 + tx] = hi;
    A3[p*768 + 256 + c0 + tx] = hi;
    A3[p*768 + 512 + c0 + tx] = lo;
  }
}

// 3x3 conv weight (O=256,C=256,9) -> bf16 B[n=k*256+o][c]
__global__ void k_prep_tapw(const float* __restrict__ w, short* __restrict__ Bm){
  int n = blockIdx.x, c = threadIdx.x;
  int k = n >> 8, o = n & 255;
  Bm[(size_t)n*256 + c] = f2bf(w[((size_t)o*256 + c)*9 + k]);
}

// ap_w1 (64,256,3,3) -> B3 (640,768) = [Bh|Bl|Bh], rows n=k*64+o, zero-pad n>=576
__global__ void k_prep_apw3(const float* __restrict__ w, short* __restrict__ B3){
  int n = blockIdx.x, c = threadIdx.x;
  short hi = 0, lo = 0;
  if (n < 576){
    int o = n & 63, k = n >> 6;
    float x = w[((size_t)o*256 + c)*9 + k];
    hi = f2bf(x);
    lo = f2bf(x - bf2f(hi));
  }
  B3[(size_t)n*768 + c] = hi;
  B3[(size_t)n*768 + 256 + c] = lo;
  B3[(size_t)n*768 + 512 + c] = hi;
}

__global__ void k_castcopy(const float* __restrict__ in, short* __restrict__ out, int n){
  int i = blockIdx.x*256 + threadIdx.x;
  if (i < n) out[i] = f2bf(in[i]);
}

// ---------------- bf16 TN GEMM with epilogues ----------------
// C[M][*] = A[M][K] x B[N][K]^T. block 256 = 4 waves (2x2), wave tile 32x64.
// EPI: 0 bf16 plain; 1 bf16 +bias; 2 bf16 relu(+bias); 3 enh gate; 4 fp32 NCHW +bias; 5 fp32 plain
template<int EPI>
__global__ __launch_bounds__(256) void k_gemm(const short* __restrict__ A,
    const short* __restrict__ B, void* __restrict__ Cv,
    const float* __restrict__ bias, const short* __restrict__ aux,
    int K, int ldc){
  int w = threadIdx.x >> 6, l = threadIdx.x & 63;
  int m0 = blockIdx.x*64 + (w & 1)*32;
  int n0 = blockIdx.y*128 + (w >> 1)*64;
  int ml = l & 15, g = l >> 4;
  f32x4 acc[2][4];
  #pragma unroll
  for (int i = 0; i < 2; ++i)
    #pragma unroll
    for (int j = 0; j < 4; ++j) acc[i][j] = (f32x4){0.f,0.f,0.f,0.f};
  const short* Ap = A + (size_t)(m0 + ml)*K + g*8;
  const short* Bp = B + (size_t)(n0 + ml)*K + g*8;
  for (int k0 = 0; k0 < K; k0 += 32){
    short8 a0 = *(const short8*)(Ap + k0);
    short8 a1 = *(const short8*)(Ap + (size_t)16*K + k0);
    short8 b0 = *(const short8*)(Bp + k0);
    short8 b1 = *(const short8*)(Bp + (size_t)16*K + k0);
    short8 b2 = *(const short8*)(Bp + (size_t)32*K + k0);
    short8 b3 = *(const short8*)(Bp + (size_t)48*K + k0);
    acc[0][0] = __builtin_amdgcn_mfma_f32_16x16x32_bf16(a0, b0, acc[0][0], 0, 0, 0);
    acc[0][1] = __builtin_amdgcn_mfma_f32_16x16x32_bf16(a0, b1, acc[0][1], 0, 0, 0);
    acc[0][2] = __builtin_amdgcn_mfma_f32_16x16x32_bf16(a0, b2, acc[0][2], 0, 0, 0);
    acc[0][3] = __builtin_amdgcn_mfma_f32_16x16x32_bf16(a0, b3, acc[0][3], 0, 0, 0);
    acc[1][0] = __builtin_amdgcn_mfma_f32_16x16x32_bf16(a1, b0, acc[1][0], 0, 0, 0);
    acc[1][1] = __builtin_amdgcn_mfma_f32_16x16x32_bf16(a1, b1, acc[1][1], 0, 0, 0);
    acc[1][2] = __builtin_amdgcn_mfma_f32_16x16x32_bf16(a1, b2, acc[1][2], 0, 0, 0);
    acc[1][3] = __builtin_amdgcn_mfma_f32_16x16x32_bf16(a1, b3, acc[1][3], 0, 0, 0);
  }
  #pragma unroll
  for (int fm = 0; fm < 2; ++fm)
    #pragma unroll
    for (int fn = 0; fn < 4; ++fn)
      #pragma unroll
      for (int r = 0; r < 4; ++r){
        int row = m0 + fm*16 + g*4 + r;
        int col = n0 + fn*16 + ml;
        float v = acc[fm][fn][r];
        if constexpr (EPI == 0){
          ((short*)Cv)[(size_t)row*ldc + col] = f2bf(v);
        } else if constexpr (EPI == 1){
          ((short*)Cv)[(size_t)row*ldc + col] = f2bf(v + bias[col]);
        } else if constexpr (EPI == 2){
          ((short*)Cv)[(size_t)row*ldc + col] = f2bf(fmaxf(v + bias[col], 0.f));
        } else if constexpr (EPI == 3){
          float f = bf2f(aux[(size_t)row*320 + col]);
          float s = 1.f/(1.f + __expf(-(v + bias[col])));
          ((short*)Cv)[(size_t)row*ldc + col] = f2bf(f * (1.f + s));
        } else if constexpr (EPI == 4){
          int b = row >> 12, hw = row & 4095;
          ((float*)Cv)[(((size_t)(b*256 + col)) << 12) + hw] = v + bias[col];
        } else {
          ((float*)Cv)[(size_t)row*ldc + col] = v;
        }
      }
}

// ---------------- angle head: tap-sum + relu + 64->1 proj ----------------
// T fp32 (8192,640), cols n=k*64+o. wave per pixel, lane=o.
__global__ void k_aph1(const float* __restrict__ T, const float* __restrict__ b1,
    const float* __restrict__ w2, const float* __restrict__ b2,
    float* __restrict__ ang){
  const int KYi[9] = {-1,-1,-1,0,0,0,1,1,1};
  const int KXi[9] = {-1,0,1,-1,0,1,-1,0,1};
  int o = threadIdx.x & 63;
  int p = blockIdx.x*4 + (threadIdx.x >> 6);
  int hw = p & 4095;
  int h = hw >> 6, w = hw & 63;
  float acc = b1[o];
  #pragma unroll
  for (int k = 0; k < 9; ++k){
    int y = h + KYi[k], x = w + KXi[k];
    if (y < 0 || y > 63 || x < 0 || x > 63) continue;
    acc += T[(size_t)(p + KYi[k]*64 + KXi[k])*640 + k*64 + o];
  }
  float v = fmaxf(acc, 0.f) * w2[o];
  float s = wsum64(v);
  if (o == 0) ang[p] = s + b2[0];
}

// ---------------- 2) angle encoding -> gateA cols 256..319 (bf16) ----------------
__global__ void k_angle_encode(const float* __restrict__ ang, const float* __restrict__ freq,
    const float* __restrict__ w1, const float* __restrict__ b1,
    const float* __restrict__ lng, const float* __restrict__ lnb,
    const float* __restrict__ w2, const float* __restrict__ b2,
    short* __restrict__ gateA){
  int lane = threadIdx.x & 63;
  int p = blockIdx.x * 4 + (threadIdx.x >> 6);
  float an = ang[p] * (2.0f / PI_F);
  int f = lane & 31;
  float ph = an * freq[f] * ((float)f * (PI_F / 32.0f));
  float emb = (lane < 32) ? __sinf(ph) : __cosf(ph);
  float h = b1[lane];
  const float* w1r = w1 + lane*64;
  #pragma unroll 8
  for (int i = 0; i < 64; ++i){
    float e = __shfl(emb, i, 64);
    h = fmaf(e, w1r[i], h);
  }
  float mu = wsum64(h) * (1.0f/64.0f);
  float d = h - mu;
  float var = wsum64(d*d) * (1.0f/64.0f);
  float hn = fmaf(d * rsqrtf(var + 1e-5f), lng[lane], lnb[lane]);
  float r = fmaxf(hn, 0.f);
  float o = b2[lane];
  const float* w2r = w2 + lane*64;
  #pragma unroll 8
  for (int i = 0; i < 64; ++i){
    float e = __shfl(r, i, 64);
    o = fmaf(e, w2r[i], o);
  }
  gateA[(size_t)p*320 + 256 + lane] = f2bf(o);
}

// ---------------- 3/4) bilinear gather on tap-features G -> cand bf16 ----------------
__global__ void k_sample(const short* __restrict__ G, const float* __restrict__ ang,
    const float* __restrict__ bias, short* __restrict__ cand){
  const float KYc[9] = {-1,-1,-1,0,0,0,1,1,1};
  const float KXc[9] = {-1,0,1,-1,0,1,-1,0,1};
  int p = blockIdx.x, hyp = blockIdx.y, o = threadIdx.x;
  float a = ang[p] + ((float)hyp - 1.0f) * (PI_F / 12.0f);
  float sn = __sinf(a), cs = __cosf(a);
  int b = p >> 12, hw = p & 4095;
  int h = hw >> 6, w = hw & 63;
  float fh = (float)h, fw = (float)w;
  float acc = bias[o];
  #pragma unroll
  for (int k = 0; k < 9; ++k){
    float py = fh + KXc[k]*sn + KYc[k]*cs;
    float px = fw + KXc[k]*cs - KYc[k]*sn;
    float y0f = floorf(py), x0f = floorf(px);
    float wy = py - y0f, wx = px - x0f;
    int y0 = (int)y0f, x0 = (int)x0f;
    const short* Gk = G + k*256 + o;
    #pragma unroll
    for (int dy = 0; dy < 2; ++dy){
      int yy = y0 + dy;
      if (yy < 0 || yy > 63) continue;
      float fy = dy ? wy : 1.f - wy;
      #pragma unroll
      for (int dx = 0; dx < 2; ++dx){
        int xx = x0 + dx;
        if (xx < 0 || xx > 63) continue;
        float fx = dx ? wx : 1.f - wx;
        acc = fmaf(fy*fx, bf2f(Gk[(size_t)(b*HWSZ + yy*64 + xx)*2304]), acc);
      }
    }
  }
  cand[((size_t)hyp*NPIX + p)*256 + o] = f2bf(acc);
}

// ---------------- 4) attention core: QKV (24576,768) bf16 -> O bf16 (8192,256) ----------------
__global__ void k_attn(const short* __restrict__ QKV, short* __restrict__ O){
  int lane = threadIdx.x & 63;
  int p = blockIdx.x*4 + (threadIdx.x >> 6);
  const short* qp = QKV + (size_t)(NPIX + p)*768 + lane*4;
  float q[4];
  { short4_t t = *(const short4_t*)qp;
    #pragma unroll
    for (int j = 0; j < 4; ++j) q[j] = bf2f(t[j]); }
  float kv[3][2][4];
  #pragma unroll
  for (int i = 0; i < 3; ++i){
    const short* rp = QKV + (size_t)(i*NPIX + p)*768 + lane*4;
    short4_t kt = *(const short4_t*)(rp + 256);
    short4_t vt = *(const short4_t*)(rp + 512);
    #pragma unroll
    for (int j = 0; j < 4; ++j){ kv[i][0][j] = bf2f(kt[j]); kv[i][1][j] = bf2f(vt[j]); }
  }
  const float sc = 0.17677669529663688f; // 1/sqrt(32)
  float s[3];
  #pragma unroll
  for (int i = 0; i < 3; ++i){
    float d = 0.f;
    #pragma unroll
    for (int j = 0; j < 4; ++j) d = fmaf(q[j], kv[i][0][j], d);
    s[i] = wsum8(d) * sc;
  }
  float m = fmaxf(s[0], fmaxf(s[1], s[2]));
  float e0 = __expf(s[0]-m), e1 = __expf(s[1]-m), e2 = __expf(s[2]-m);
  float inv = 1.f/(e0+e1+e2);
  short4_t ot;
  #pragma unroll
  for (int j = 0; j < 4; ++j)
    ot[j] = f2bf((e0*kv[0][1][j] + e1*kv[1][1][j] + e2*kv[2][1][j]) * inv);
  *(short4_t*)(O + (size_t)p*256 + lane*4) = ot;
}

// ---------------- 6a2) shift-add of tap outputs H -> t fp32 ----------------
__global__ void k_shiftadd(const short* __restrict__ Hm, const float* __restrict__ b1,
    float* __restrict__ t){
  const int KYi[9] = {-1,-1,-1,0,0,0,1,1,1};
  const int KXi[9] = {-1,0,1,-1,0,1,-1,0,1};
  int p = blockIdx.x, o = threadIdx.x;
  int hw = p & 4095;
  int h = hw >> 6, w = hw & 63;
  float acc = b1[o];
  #pragma unroll
  for (int k = 0; k < 9; ++k){
    int y = h + KYi[k], x = w + KXi[k];
    if (y < 0 || y > 63 || x < 0 || x > 63) continue;
    acc += bf2f(Hm[(size_t)(p + KYi[k]*64 + KXi[k])*2304 + k*256 + o]);
  }
  t[(size_t)p*256 + o] = acc;
}

// ---------------- 6b) group-norm stats ----------------
__global__ void k_gnstat(const float* __restrict__ t, float* __restrict__ stat){
  int bg = blockIdx.x;
  int b = bg >> 5, g = bg & 31;
  const float* base = t + (size_t)b*HWSZ*256 + g*8;
  float s = 0.f, s2 = 0.f;
  for (int idx = threadIdx.x; idx < 8*HWSZ; idx += 256){
    int p = idx >> 3, cc = idx & 7;
    float v = base[(size_t)p*256 + cc];
    s += v; s2 = fmaf(v, v, s2);
  }
  s = wsum64(s); s2 = wsum64(s2);
  __shared__ float rs[4], rs2[4];
  int wid = threadIdx.x >> 6;
  if ((threadIdx.x & 63) == 0){ rs[wid] = s; rs2[wid] = s2; }
  __syncthreads();
  if (threadIdx.x == 0){
    float S = rs[0]+rs[1]+rs[2]+rs[3];
    float S2 = rs2[0]+rs2[1]+rs2[2]+rs2[3];
    float mean = S * (1.f/32768.f);
    float var = S2 * (1.f/32768.f) - mean*mean;
    stat[bg*2]   = mean;
    stat[bg*2+1] = rsqrtf(var + 1e-5f);
  }
}

// ---------------- 6c) GN + relu -> bf16 ----------------
__global__ void k_gnrelu(const float* __restrict__ t, const float* __restrict__ stat,
    const float* __restrict__ gng, const float* __restrict__ gnb,
    short* __restrict__ a){
  int p = blockIdx.x, c = threadIdx.x;
  int b = p >> 12, g = c >> 3;
  float mean = stat[(b*32+g)*2], rstd = stat[(b*32+g)*2+1];
  float gg = gng[c] * rstd;
  float bb = gnb[c] - mean*gg;
  float v = t[(size_t)p*256 + c];
  a[(size_t)p*256 + c] = f2bf(fmaxf(fmaf(v, gg, bb), 0.f));
}

// ---------------- launch ----------------
extern "C" void kernel_launch(void* const* d_in, const int* in_sizes, int n_in,
                              void* d_out, int out_size, void* d_ws, size_t ws_size,
                              hipStream_t stream){
  (void)in_sizes; (void)n_in; (void)out_size; (void)ws_size;
  const float* features   = (const float*)d_in[0];
  const float* ap_w1      = (const float*)d_in[1];
  const float* ap_b1      = (const float*)d_in[2];
  const float* ap_w2      = (const float*)d_in[3];
  const float* ap_b2      = (const float*)d_in[4];
  const float* freq       = (const float*)d_in[5];
  const float* ae_w1      = (const float*)d_in[6];
  const float* ae_b1      = (const float*)d_in[7];
  const float* ae_ln_g    = (const float*)d_in[8];
  const float* ae_ln_b    = (const float*)d_in[9];
  const float* ae_w2      = (const float*)d_in[10];
  const float* ae_b2      = (const float*)d_in[11];
  const float* dc_w       = (const float*)d_in[12];
  const float* dc_b       = (const float*)d_in[13];
  const float* attn_in_w  = (const float*)d_in[14];
  const float* attn_in_b  = (const float*)d_in[15];
  const float* attn_out_w = (const float*)d_in[16];
  const float* attn_out_b = (const float*)d_in[17];
  const float* ja_w1      = (const float*)d_in[18];
  const float* ja_b1      = (const float*)d_in[19];
  const float* ja_w2      = (const float*)d_in[20];
  const float* ja_b2      = (const float*)d_in[21];
  const float* op_w1      = (const float*)d_in[22];
  const float* op_b1      = (const float*)d_in[23];
  const float* gn_g       = (const float*)d_in[24];
  const float* gn_b       = (const float*)d_in[25];
  const float* op_w2      = (const float*)d_in[26];
  const float* op_b2      = (const float*)d_in[27];

  char* base = (char*)d_ws;
  #define ALLOC(ty, name, elems) ty* name = (ty*)base; base += (size_t)(elems)*sizeof(ty);
  ALLOC(short, feat_bf, 8192*256)
  ALLOC(short, Bdc,     2304*256)
  ALLOC(short, Bop,     2304*256)
  ALLOC(short, B3ap,    640*768)
  ALLOC(short, inw_bf,  768*256)
  ALLOC(short, wot_bf,  256*256)
  ALLOC(short, jw1_bf,  256*320)
  ALLOC(short, jw2_bf,  256*256)
  ALLOC(short, wop2_bf, 256*256)
  ALLOC(short, Gbuf,    24576*768)   // serves: T_ap(fp32 8192x640) -> G -> QKV -> H
  ALLOC(short, cand_bf, 3*8192*256)  // also aliased as A3 (8192x768) before sampling
  ALLOC(short, O_bf,    8192*256)
  ALLOC(short, gateA,   8192*320)
  ALLOC(short, hid_bf,  8192*256)
  ALLOC(short, enh_bf,  8192*256)
  ALLOC(float, angbuf,  8192)
  ALLOC(float, tbuf,    8192*256)
  ALLOC(float, gstat,   128)
  ALLOC(short, a_bf,    8192*256)
  #undef ALLOC
  short* A3 = cand_bf;          // 8192*768, dead before cand written
  float* T_ap = (float*)Gbuf;   // 8192*640 fp32

  dim3 t32(32, 8);
  k_nchw_split<<<dim3(128,8,2), t32, 0, stream>>>(features, feat_bf, A3);
  k_prep_tapw<<<2304, 256, 0, stream>>>(dc_w,  Bdc);
  k_prep_tapw<<<2304, 256, 0, stream>>>(op_w1, Bop);
  k_prep_apw3<<<640, 256, 0, stream>>>(ap_w1, B3ap);
  k_castcopy<<<768, 256, 0, stream>>>(attn_in_w,  inw_bf,  768*256);
  k_castcopy<<<256, 256, 0, stream>>>(attn_out_w, wot_bf,  256*256);
  k_castcopy<<<320, 256, 0, stream>>>(ja_w1,      jw1_bf,  256*320);
  k_castcopy<<<256, 256, 0, stream>>>(ja_w2,      jw2_bf,  256*256);
  k_castcopy<<<256, 256, 0, stream>>>(op_w2,      wop2_bf, 256*256);

  // angle head: T = A3 x B3ap^T (compensated bf16, fp32 out)
  k_gemm<5><<<dim3(128,5), 256, 0, stream>>>(A3, B3ap, T_ap, nullptr, nullptr, 768, 640);
  k_aph1<<<2048, 256, 0, stream>>>(T_ap, ap_b1, ap_w2, ap_b2, angbuf);
  k_angle_encode<<<2048, 256, 0, stream>>>(angbuf, freq, ae_w1, ae_b1, ae_ln_g, ae_ln_b,
                                           ae_w2, ae_b2, gateA);
  // G = feat x Bdc^T (8192,2304) ; sample -> cand
  k_gemm<0><<<dim3(128,18), 256, 0, stream>>>(feat_bf, Bdc, Gbuf, nullptr, nullptr, 256, 2304);
  k_sample<<<dim3(NPIX,3), 256, 0, stream>>>(Gbuf, angbuf, dc_b, cand_bf);
  // QKV = cand x in_w^T + inb  (24576,768)
  k_gemm<1><<<dim3(384,6), 256, 0, stream>>>(cand_bf, inw_bf, Gbuf, attn_in_b, nullptr, 256, 768);
  k_attn<<<2048, 256, 0, stream>>>(Gbuf, O_bf);
  // fused = O x out_w^T + outb -> gateA cols 0..255
  k_gemm<1><<<dim3(128,2), 256, 0, stream>>>(O_bf, wot_bf, gateA, attn_out_b, nullptr, 256, 320);
  // hid = relu(gateA x ja_w1^T + b1)
  k_gemm<2><<<dim3(128,2), 256, 0, stream>>>(gateA, jw1_bf, hid_bf, ja_b1, nullptr, 320, 256);
  // enh = fused * (1 + sigmoid(hid x ja_w2^T + b2))
  k_gemm<3><<<dim3(128,2), 256, 0, stream>>>(hid_bf, jw2_bf, enh_bf, ja_b2, gateA, 256, 256);
  // H = enh x Bop^T (8192,2304)
  k_gemm<0><<<dim3(128,18), 256, 0, stream>>>(enh_bf, Bop, Gbuf, nullptr, nullptr, 256, 2304);
  k_shiftadd<<<NPIX, 256, 0, stream>>>(Gbuf, op_b1, tbuf);
  k_gnstat<<<64, 256, 0, stream>>>(tbuf, gstat);
  k_gnrelu<<<NPIX, 256, 0, stream>>>(tbuf, gstat, gn_g, gn_b, a_bf);
  // out = GNrelu x op_w2^T + b2, NCHW fp32
  k_gemm<4><<<dim3(128,2), 256, 0, stream>>>(a_bf, wop2_bf, (float*)d_out, op_b2, nullptr, 256, 256);
}

// Round 4
// 435.259 us; speedup vs baseline: 5.9383x; 1.2206x over previous
//
#include <hip/hip_runtime.h>

#define PI_F 3.14159265358979323846f
#define HWSZ 4096   // H*W
#define NPIX 8192   // B*H*W

typedef __attribute__((ext_vector_type(8))) short short8;
typedef __attribute__((ext_vector_type(4))) short short4_t;
typedef __attribute__((ext_vector_type(4))) float f32x4;

__device__ __forceinline__ short f2bf(float x){
  unsigned u = __float_as_uint(x);
  unsigned r = (u + 0x7FFFu + ((u >> 16) & 1u)) >> 16;
  return (short)r;
}
__device__ __forceinline__ float bf2f(short v){
  return __uint_as_float(((unsigned)(unsigned short)v) << 16);
}

__device__ __forceinline__ float wsum64(float v){
  #pragma unroll
  for (int m = 32; m >= 1; m >>= 1) v += __shfl_xor(v, m, 64);
  return v;
}
__device__ __forceinline__ float wsum8(float v){
  v += __shfl_xor(v, 1, 64);
  v += __shfl_xor(v, 2, 64);
  v += __shfl_xor(v, 4, 64);
  return v;
}

// ---------------- prep kernels ----------------
// features (B,256,H,W) -> feat_bf (B,H,W,256) hi ; A3 (p,768)=[hi|hi|lo]
__global__ void k_nchw_split(const float* __restrict__ in, short* __restrict__ feat_bf,
    short* __restrict__ A3){
  __shared__ float tile[32][33];
  int b = blockIdx.z;
  int p0 = blockIdx.x * 32, c0 = blockIdx.y * 32;
  int tx = threadIdx.x, ty = threadIdx.y;
  #pragma unroll
  for (int i = ty; i < 32; i += 8)
    tile[i][tx] = in[((size_t)b*256 + c0 + i)*HWSZ + p0 + tx];
  __syncthreads();
  #pragma unroll
  for (int i = ty; i < 32; i += 8){
    float x = tile[tx][i];
    short hi = f2bf(x);
    short lo = f2bf(x - bf2f(hi));
    size_t p = (size_t)b*HWSZ + p0 + i;
    feat_bf[p*256 + c0 + tx] = hi;
    A3[p*768 + c0 + tx] = hi;
    A3[p*768 + 256 + c0 + tx] = hi;
    A3[p*768 + 512 + c0 + tx] = lo;
  }
}

// 3x3 conv weight (O=256,C=256,9) -> bf16 B[n=k*256+o][c] ; coalesced via LDS
__global__ void k_prep_tapw(const float* __restrict__ w, short* __restrict__ Bm){
  __shared__ short tile[9][256];
  int o = blockIdx.x;
  const float* wo = w + (size_t)o*2304;
  for (int i = threadIdx.x; i < 2304; i += 256){
    int c = i / 9, k = i - c*9;
    tile[k][c] = f2bf(wo[i]);
  }
  __syncthreads();
  for (int i = threadIdx.x; i < 2304; i += 256){
    int k = i >> 8, c = i & 255;
    Bm[((size_t)(k*256 + o))*256 + c] = tile[k][c];
  }
}

// ap_w1 (64,256,3,3) -> B3 (640,768) = [Bh|Bl|Bh], rows n=k*64+o, zero-pad n>=576
__global__ void k_prep_apw3(const float* __restrict__ w, short* __restrict__ B3){
  int n = blockIdx.x, c = threadIdx.x;
  short hi = 0, lo = 0;
  if (n < 576){
    int o = n & 63, k = n >> 6;
    float x = w[((size_t)o*256 + c)*9 + k];
    hi = f2bf(x);
    lo = f2bf(x - bf2f(hi));
  }
  B3[(size_t)n*768 + c] = hi;
  B3[(size_t)n*768 + 256 + c] = lo;
  B3[(size_t)n*768 + 512 + c] = hi;
}

__global__ void k_castcopy(const float* __restrict__ in, short* __restrict__ out, int n){
  int i = blockIdx.x*256 + threadIdx.x;
  if (i < n) out[i] = f2bf(in[i]);
}

// ---------------- bf16 TN GEMM with epilogues ----------------
// C[M][*] = A[M][K] x B[N][K]^T. block 256 = 4 waves (2x2), wave tile 32x64.
// EPI: 0 bf16 plain; 1 bf16 +bias; 2 bf16 relu(+bias); 3 enh gate; 4 fp32 NCHW +bias; 5 fp32 plain
template<int EPI>
__global__ __launch_bounds__(256) void k_gemm(const short* __restrict__ A,
    const short* __restrict__ B, void* __restrict__ Cv,
    const float* __restrict__ bias, const short* __restrict__ aux,
    int K, int ldc){
  int w = threadIdx.x >> 6, l = threadIdx.x & 63;
  int m0 = blockIdx.x*64 + (w & 1)*32;
  int n0 = blockIdx.y*128 + (w >> 1)*64;
  int ml = l & 15, g = l >> 4;
  f32x4 acc[2][4];
  #pragma unroll
  for (int i = 0; i < 2; ++i)
    #pragma unroll
    for (int j = 0; j < 4; ++j) acc[i][j] = (f32x4){0.f,0.f,0.f,0.f};
  const short* Ap = A + (size_t)(m0 + ml)*K + g*8;
  const short* Bp = B + (size_t)(n0 + ml)*K + g*8;
  for (int k0 = 0; k0 < K; k0 += 32){
    short8 a0 = *(const short8*)(Ap + k0);
    short8 a1 = *(const short8*)(Ap + (size_t)16*K + k0);
    short8 b0 = *(const short8*)(Bp + k0);
    short8 b1 = *(const short8*)(Bp + (size_t)16*K + k0);
    short8 b2 = *(const short8*)(Bp + (size_t)32*K + k0);
    short8 b3 = *(const short8*)(Bp + (size_t)48*K + k0);
    acc[0][0] = __builtin_amdgcn_mfma_f32_16x16x32_bf16(a0, b0, acc[0][0], 0, 0, 0);
    acc[0][1] = __builtin_amdgcn_mfma_f32_16x16x32_bf16(a0, b1, acc[0][1], 0, 0, 0);
    acc[0][2] = __builtin_amdgcn_mfma_f32_16x16x32_bf16(a0, b2, acc[0][2], 0, 0, 0);
    acc[0][3] = __builtin_amdgcn_mfma_f32_16x16x32_bf16(a0, b3, acc[0][3], 0, 0, 0);
    acc[1][0] = __builtin_amdgcn_mfma_f32_16x16x32_bf16(a1, b0, acc[1][0], 0, 0, 0);
    acc[1][1] = __builtin_amdgcn_mfma_f32_16x16x32_bf16(a1, b1, acc[1][1], 0, 0, 0);
    acc[1][2] = __builtin_amdgcn_mfma_f32_16x16x32_bf16(a1, b2, acc[1][2], 0, 0, 0);
    acc[1][3] = __builtin_amdgcn_mfma_f32_16x16x32_bf16(a1, b3, acc[1][3], 0, 0, 0);
  }
  #pragma unroll
  for (int fm = 0; fm < 2; ++fm)
    #pragma unroll
    for (int fn = 0; fn < 4; ++fn)
      #pragma unroll
      for (int r = 0; r < 4; ++r){
        int row = m0 + fm*16 + g*4 + r;
        int col = n0 + fn*16 + ml;
        float v = acc[fm][fn][r];
        if constexpr (EPI == 0){
          ((short*)Cv)[(size_t)row*ldc + col] = f2bf(v);
        } else if constexpr (EPI == 1){
          ((short*)Cv)[(size_t)row*ldc + col] = f2bf(v + bias[col]);
        } else if constexpr (EPI == 2){
          ((short*)Cv)[(size_t)row*ldc + col] = f2bf(fmaxf(v + bias[col], 0.f));
        } else if constexpr (EPI == 3){
          float f = bf2f(aux[(size_t)row*320 + col]);
          float s = 1.f/(1.f + __expf(-(v + bias[col])));
          ((short*)Cv)[(size_t)row*ldc + col] = f2bf(f * (1.f + s));
        } else if constexpr (EPI == 4){
          int b = row >> 12, hw = row & 4095;
          ((float*)Cv)[(((size_t)(b*256 + col)) << 12) + hw] = v + bias[col];
        } else {
          ((float*)Cv)[(size_t)row*ldc + col] = v;
        }
      }
}

// ---------------- angle head: tap-sum + relu + 64->1 proj ----------------
__global__ void k_aph1(const float* __restrict__ T, const float* __restrict__ b1,
    const float* __restrict__ w2, const float* __restrict__ b2,
    float* __restrict__ ang){
  const int KYi[9] = {-1,-1,-1,0,0,0,1,1,1};
  const int KXi[9] = {-1,0,1,-1,0,1,-1,0,1};
  int o = threadIdx.x & 63;
  int p = blockIdx.x*4 + (threadIdx.x >> 6);
  int hw = p & 4095;
  int h = hw >> 6, w = hw & 63;
  float acc = b1[o];
  #pragma unroll
  for (int k = 0; k < 9; ++k){
    int y = h + KYi[k], x = w + KXi[k];
    if (y < 0 || y > 63 || x < 0 || x > 63) continue;
    acc += T[(size_t)(p + KYi[k]*64 + KXi[k])*640 + k*64 + o];
  }
  float v = fmaxf(acc, 0.f) * w2[o];
  float s = wsum64(v);
  if (o == 0) ang[p] = s + b2[0];
}

// ---------------- 2) angle encoding -> gateA cols 256..319 (bf16) ----------------
__global__ void k_angle_encode(const float* __restrict__ ang, const float* __restrict__ freq,
    const float* __restrict__ w1, const float* __restrict__ b1,
    const float* __restrict__ lng, const float* __restrict__ lnb,
    const float* __restrict__ w2, const float* __restrict__ b2,
    short* __restrict__ gateA){
  int lane = threadIdx.x & 63;
  int p = blockIdx.x * 4 + (threadIdx.x >> 6);
  float an = ang[p] * (2.0f / PI_F);
  int f = lane & 31;
  float ph = an * freq[f] * ((float)f * (PI_F / 32.0f));
  float emb = (lane < 32) ? __sinf(ph) : __cosf(ph);
  float h = b1[lane];
  const float* w1r = w1 + lane*64;
  #pragma unroll 8
  for (int i = 0; i < 64; ++i){
    float e = __shfl(emb, i, 64);
    h = fmaf(e, w1r[i], h);
  }
  float mu = wsum64(h) * (1.0f/64.0f);
  float d = h - mu;
  float var = wsum64(d*d) * (1.0f/64.0f);
  float hn = fmaf(d * rsqrtf(var + 1e-5f), lng[lane], lnb[lane]);
  float r = fmaxf(hn, 0.f);
  float o = b2[lane];
  const float* w2r = w2 + lane*64;
  #pragma unroll 8
  for (int i = 0; i < 64; ++i){
    float e = __shfl(r, i, 64);
    o = fmaf(e, w2r[i], o);
  }
  gateA[(size_t)p*320 + 256 + lane] = f2bf(o);
}

// ---------------- 3/4) bilinear gather on G: 4 px/block, 3 hyps, ushort4, XCD bands --------
__global__ __launch_bounds__(256) void k_sample(const short* __restrict__ G,
    const float* __restrict__ ang, const float* __restrict__ bias,
    short* __restrict__ cand){
  const float KYc[9] = {-1,-1,-1,0,0,0,1,1,1};
  const float KXc[9] = {-1,0,1,-1,0,1,-1,0,1};
  int id = blockIdx.x;                       // 2048 blocks
  int sw = (id & 7) * 256 + (id >> 3);       // bijective XCD band swizzle
  int p = sw * 4 + (threadIdx.x >> 6);
  int lane = threadIdx.x & 63;
  int c4 = lane * 4;
  int b = p >> 12, hw = p & 4095;
  int h = hw >> 6, w = hw & 63;
  float fh = (float)h, fw = (float)w;
  float a0 = ang[p];
  float4 bs = *(const float4*)(bias + c4);
  float acc[3][4];
  #pragma unroll
  for (int i = 0; i < 3; ++i){
    acc[i][0] = bs.x; acc[i][1] = bs.y; acc[i][2] = bs.z; acc[i][3] = bs.w;
  }
  const short* Gb = G + (size_t)b*HWSZ*2304 + c4;
  #pragma unroll 1
  for (int hyp = 0; hyp < 3; ++hyp){
    float a = a0 + ((float)hyp - 1.0f) * (PI_F / 12.0f);
    float sn = __sinf(a), cs = __cosf(a);
    #pragma unroll
    for (int k = 0; k < 9; ++k){
      float py = fh + KXc[k]*sn + KYc[k]*cs;
      float px = fw + KXc[k]*cs - KYc[k]*sn;
      float y0f = floorf(py), x0f = floorf(px);
      float wy = py - y0f, wx = px - x0f;
      int y0 = (int)y0f, x0 = (int)x0f;
      const short* Gk = Gb + k*256;
      #pragma unroll
      for (int dy = 0; dy < 2; ++dy){
        int yy = y0 + dy;
        if (yy < 0 || yy > 63) continue;
        float fy = dy ? wy : 1.f - wy;
        #pragma unroll
        for (int dx = 0; dx < 2; ++dx){
          int xx = x0 + dx;
          if (xx < 0 || xx > 63) continue;
          float fxy = fy * (dx ? wx : 1.f - wx);
          short4_t v = *(const short4_t*)(Gk + (size_t)(yy*64 + xx)*2304);
          acc[hyp][0] = fmaf(fxy, bf2f(v[0]), acc[hyp][0]);
          acc[hyp][1] = fmaf(fxy, bf2f(v[1]), acc[hyp][1]);
          acc[hyp][2] = fmaf(fxy, bf2f(v[2]), acc[hyp][2]);
          acc[hyp][3] = fmaf(fxy, bf2f(v[3]), acc[hyp][3]);
        }
      }
    }
  }
  #pragma unroll
  for (int hyp = 0; hyp < 3; ++hyp){
    short4_t o;
    #pragma unroll
    for (int j = 0; j < 4; ++j) o[j] = f2bf(acc[hyp][j]);
    *(short4_t*)(cand + ((size_t)hyp*NPIX + p)*256 + c4) = o;
  }
}

// ---------------- 4) attention core: Q (8192,256), KV (24576,512) -> O bf16 ----------------
__global__ void k_attn(const short* __restrict__ Q, const short* __restrict__ KV,
    short* __restrict__ O){
  int lane = threadIdx.x & 63;
  int p = blockIdx.x*4 + (threadIdx.x >> 6);
  float q[4];
  { short4_t t = *(const short4_t*)(Q + (size_t)p*256 + lane*4);
    #pragma unroll
    for (int j = 0; j < 4; ++j) q[j] = bf2f(t[j]); }
  float kv[3][2][4];
  #pragma unroll
  for (int i = 0; i < 3; ++i){
    const short* rp = KV + (size_t)(i*NPIX + p)*512 + lane*4;
    short4_t kt = *(const short4_t*)rp;
    short4_t vt = *(const short4_t*)(rp + 256);
    #pragma unroll
    for (int j = 0; j < 4; ++j){ kv[i][0][j] = bf2f(kt[j]); kv[i][1][j] = bf2f(vt[j]); }
  }
  const float sc = 0.17677669529663688f; // 1/sqrt(32)
  float s[3];
  #pragma unroll
  for (int i = 0; i < 3; ++i){
    float d = 0.f;
    #pragma unroll
    for (int j = 0; j < 4; ++j) d = fmaf(q[j], kv[i][0][j], d);
    s[i] = wsum8(d) * sc;
  }
  float m = fmaxf(s[0], fmaxf(s[1], s[2]));
  float e0 = __expf(s[0]-m), e1 = __expf(s[1]-m), e2 = __expf(s[2]-m);
  float inv = 1.f/(e0+e1+e2);
  short4_t ot;
  #pragma unroll
  for (int j = 0; j < 4; ++j)
    ot[j] = f2bf((e0*kv[0][1][j] + e1*kv[1][1][j] + e2*kv[2][1][j]) * inv);
  *(short4_t*)(O + (size_t)p*256 + lane*4) = ot;
}

// ---------------- 6a2) shift-add of tap outputs H -> t fp32 (4 px/block, ushort4) -------
__global__ __launch_bounds__(256) void k_shiftadd(const short* __restrict__ Hm,
    const float* __restrict__ b1, float* __restrict__ t){
  const int KYi[9] = {-1,-1,-1,0,0,0,1,1,1};
  const int KXi[9] = {-1,0,1,-1,0,1,-1,0,1};
  int id = blockIdx.x;
  int sw = (id & 7) * 256 + (id >> 3);
  int p = sw * 4 + (threadIdx.x >> 6);
  int lane = threadIdx.x & 63;
  int c4 = lane * 4;
  int hw = p & 4095;
  int h = hw >> 6, w = hw & 63;
  float4 bs = *(const float4*)(b1 + c4);
  float acc[4] = {bs.x, bs.y, bs.z, bs.w};
  const short* Hp = Hm + (size_t)p*2304 + c4;
  #pragma unroll
  for (int k = 0; k < 9; ++k){
    int y = h + KYi[k], x = w + KXi[k];
    if (y < 0 || y > 63 || x < 0 || x > 63) continue;
    short4_t v = *(const short4_t*)(Hp + (size_t)(KYi[k]*64 + KXi[k])*2304 + k*256);
    #pragma unroll
    for (int j = 0; j < 4; ++j) acc[j] += bf2f(v[j]);
  }
  *(float4*)(t + (size_t)p*256 + c4) = make_float4(acc[0], acc[1], acc[2], acc[3]);
}

// ---------------- 6b) group-norm stats ----------------
__global__ void k_gnstat(const float* __restrict__ t, float* __restrict__ stat){
  int bg = blockIdx.x;
  int b = bg >> 5, g = bg & 31;
  const float* base = t + (size_t)b*HWSZ*256 + g*8;
  float s = 0.f, s2 = 0.f;
  for (int idx = threadIdx.x; idx < 8*HWSZ; idx += 256){
    int p = idx >> 3, cc = idx & 7;
    float v = base[(size_t)p*256 + cc];
    s += v; s2 = fmaf(v, v, s2);
  }
  s = wsum64(s); s2 = wsum64(s2);
  __shared__ float rs[4], rs2[4];
  int wid = threadIdx.x >> 6;
  if ((threadIdx.x & 63) == 0){ rs[wid] = s; rs2[wid] = s2; }
  __syncthreads();
  if (threadIdx.x == 0){
    float S = rs[0]+rs[1]+rs[2]+rs[3];
    float S2 = rs2[0]+rs2[1]+rs2[2]+rs2[3];
    float mean = S * (1.f/32768.f);
    float var = S2 * (1.f/32768.f) - mean*mean;
    stat[bg*2]   = mean;
    stat[bg*2+1] = rsqrtf(var + 1e-5f);
  }
}

// ---------------- 6c) GN + relu -> bf16 ----------------
__global__ void k_gnrelu(const float* __restrict__ t, const float* __restrict__ stat,
    const float* __restrict__ gng, const float* __restrict__ gnb,
    short* __restrict__ a){
  int p = blockIdx.x, c = threadIdx.x;
  int b = p >> 12, g = c >> 3;
  float mean = stat[(b*32+g)*2], rstd = stat[(b*32+g)*2+1];
  float gg = gng[c] * rstd;
  float bb = gnb[c] - mean*gg;
  float v = t[(size_t)p*256 + c];
  a[(size_t)p*256 + c] = f2bf(fmaxf(fmaf(v, gg, bb), 0.f));
}

// ---------------- launch ----------------
extern "C" void kernel_launch(void* const* d_in, const int* in_sizes, int n_in,
                              void* d_out, int out_size, void* d_ws, size_t ws_size,
                              hipStream_t stream){
  (void)in_sizes; (void)n_in; (void)out_size; (void)ws_size;
  const float* features   = (const float*)d_in[0];
  const float* ap_w1      = (const float*)d_in[1];
  const float* ap_b1      = (const float*)d_in[2];
  const float* ap_w2      = (const float*)d_in[3];
  const float* ap_b2      = (const float*)d_in[4];
  const float* freq       = (const float*)d_in[5];
  const float* ae_w1      = (const float*)d_in[6];
  const float* ae_b1      = (const float*)d_in[7];
  const float* ae_ln_g    = (const float*)d_in[8];
  const float* ae_ln_b    = (const float*)d_in[9];
  const float* ae_w2      = (const float*)d_in[10];
  const float* ae_b2      = (const float*)d_in[11];
  const float* dc_w       = (const float*)d_in[12];
  const float* dc_b       = (const float*)d_in[13];
  const float* attn_in_w  = (const float*)d_in[14];
  const float* attn_in_b  = (const float*)d_in[15];
  const float* attn_out_w = (const float*)d_in[16];
  const float* attn_out_b = (const float*)d_in[17];
  const float* ja_w1      = (const float*)d_in[18];
  const float* ja_b1      = (const float*)d_in[19];
  const float* ja_w2      = (const float*)d_in[20];
  const float* ja_b2      = (const float*)d_in[21];
  const float* op_w1      = (const float*)d_in[22];
  const float* op_b1      = (const float*)d_in[23];
  const float* gn_g       = (const float*)d_in[24];
  const float* gn_b       = (const float*)d_in[25];
  const float* op_w2      = (const float*)d_in[26];
  const float* op_b2      = (const float*)d_in[27];

  char* base = (char*)d_ws;
  #define ALLOC(ty, name, elems) ty* name = (ty*)base; base += (size_t)(elems)*sizeof(ty);
  ALLOC(short, feat_bf, 8192*256)
  ALLOC(short, Bdc,     2304*256)
  ALLOC(short, Bop,     2304*256)
  ALLOC(short, B3ap,    640*768)
  ALLOC(short, inw_bf,  768*256)
  ALLOC(short, wot_bf,  256*256)
  ALLOC(short, jw1_bf,  256*320)
  ALLOC(short, jw2_bf,  256*256)
  ALLOC(short, wop2_bf, 256*256)
  ALLOC(short, Gbuf,    24576*768)   // serves: T_ap(fp32) -> G -> KV/Q -> H
  ALLOC(short, cand_bf, 3*8192*256)  // aliased as A3 (8192x768) before sampling
  ALLOC(short, O_bf,    8192*256)
  ALLOC(short, gateA,   8192*320)
  ALLOC(short, hid_bf,  8192*256)
  ALLOC(short, enh_bf,  8192*256)
  ALLOC(float, angbuf,  8192)
  ALLOC(float, tbuf,    8192*256)
  ALLOC(float, gstat,   128)
  ALLOC(short, a_bf,    8192*256)
  #undef ALLOC
  short* A3 = cand_bf;                      // 8192*768, dead before cand written
  float* T_ap = (float*)Gbuf;               // 8192*640 fp32
  short* KVbuf = Gbuf;                      // 24576*512 bf16
  short* Qbuf  = Gbuf + (size_t)24576*512;  // 8192*256 bf16

  dim3 t32(32, 8);
  k_nchw_split<<<dim3(128,8,2), t32, 0, stream>>>(features, feat_bf, A3);
  k_prep_tapw<<<256, 256, 0, stream>>>(dc_w,  Bdc);
  k_prep_tapw<<<256, 256, 0, stream>>>(op_w1, Bop);
  k_prep_apw3<<<640, 256, 0, stream>>>(ap_w1, B3ap);
  k_castcopy<<<768, 256, 0, stream>>>(attn_in_w,  inw_bf,  768*256);
  k_castcopy<<<256, 256, 0, stream>>>(attn_out_w, wot_bf,  256*256);
  k_castcopy<<<320, 256, 0, stream>>>(ja_w1,      jw1_bf,  256*320);
  k_castcopy<<<256, 256, 0, stream>>>(ja_w2,      jw2_bf,  256*256);
  k_castcopy<<<256, 256, 0, stream>>>(op_w2,      wop2_bf, 256*256);

  // angle head: T = A3 x B3ap^T (compensated bf16, fp32 out)
  k_gemm<5><<<dim3(128,5), 256, 0, stream>>>(A3, B3ap, T_ap, nullptr, nullptr, 768, 640);
  k_aph1<<<2048, 256, 0, stream>>>(T_ap, ap_b1, ap_w2, ap_b2, angbuf);
  k_angle_encode<<<2048, 256, 0, stream>>>(angbuf, freq, ae_w1, ae_b1, ae_ln_g, ae_ln_b,
                                           ae_w2, ae_b2, gateA);
  // G = feat x Bdc^T (8192,2304) ; sample -> cand
  k_gemm<0><<<dim3(128,18), 256, 0, stream>>>(feat_bf, Bdc, Gbuf, nullptr, nullptr, 256, 2304);
  k_sample<<<2048, 256, 0, stream>>>(Gbuf, angbuf, dc_b, cand_bf);
  // KV = cand x in_w[256:768]^T + inb[256:768]  (24576,512)
  k_gemm<1><<<dim3(384,4), 256, 0, stream>>>(cand_bf, inw_bf + (size_t)256*256, KVbuf,
                                             attn_in_b + 256, nullptr, 256, 512);
  // Q = cand[hyp1] x in_w[0:256]^T + inb[0:256]  (8192,256)
  k_gemm<1><<<dim3(128,2), 256, 0, stream>>>(cand_bf + (size_t)NPIX*256, inw_bf, Qbuf,
                                             attn_in_b, nullptr, 256, 256);
  k_attn<<<2048, 256, 0, stream>>>(Qbuf, KVbuf, O_bf);
  // fused = O x out_w^T + outb -> gateA cols 0..255
  k_gemm<1><<<dim3(128,2), 256, 0, stream>>>(O_bf, wot_bf, gateA, attn_out_b, nullptr, 256, 320);
  // hid = relu(gateA x ja_w1^T + b1)
  k_gemm<2><<<dim3(128,2), 256, 0, stream>>>(gateA, jw1_bf, hid_bf, ja_b1, nullptr, 320, 256);
  // enh = fused * (1 + sigmoid(hid x ja_w2^T + b2))
  k_gemm<3><<<dim3(128,2), 256, 0, stream>>>(hid_bf, jw2_bf, enh_bf, ja_b2, gateA, 256, 256);
  // H = enh x Bop^T (8192,2304)
  k_gemm<0><<<dim3(128,18), 256, 0, stream>>>(enh_bf, Bop, Gbuf, nullptr, nullptr, 256, 2304);
  k_shiftadd<<<2048, 256, 0, stream>>>(Gbuf, op_b1, tbuf);
  k_gnstat<<<64, 256, 0, stream>>>(tbuf, gstat);
  k_gnrelu<<<NPIX, 256, 0, stream>>>(tbuf, gstat, gn_g, gn_b, a_bf);
  // out = GNrelu x op_w2^T + b2, NCHW fp32
  k_gemm<4><<<dim3(128,2), 256, 0, stream>>>(a_bf, wop2_bf, (float*)d_out, op_b2, nullptr, 256, 256);
}

// Round 5
// 395.455 us; speedup vs baseline: 6.5359x; 1.1007x over previous
//
#include <hip/hip_runtime.h>

#define PI_F 3.14159265358979323846f
#define HWSZ 4096   // H*W
#define NPIX 8192   // B*H*W

typedef __attribute__((ext_vector_type(8))) short short8;
typedef __attribute__((ext_vector_type(4))) short short4_t;
typedef __attribute__((ext_vector_type(4))) float f32x4;

__device__ __forceinline__ short f2bf(float x){
  unsigned u = __float_as_uint(x);
  unsigned r = (u + 0x7FFFu + ((u >> 16) & 1u)) >> 16;
  return (short)r;
}
__device__ __forceinline__ float bf2f(short v){
  return __uint_as_float(((unsigned)(unsigned short)v) << 16);
}

__device__ __forceinline__ float wsum64(float v){
  #pragma unroll
  for (int m = 32; m >= 1; m >>= 1) v += __shfl_xor(v, m, 64);
  return v;
}
__device__ __forceinline__ float wsum8(float v){
  v += __shfl_xor(v, 1, 64);
  v += __shfl_xor(v, 2, 64);
  v += __shfl_xor(v, 4, 64);
  return v;
}

// ---------------- prep kernels ----------------
// features (B,256,H,W) -> feat_bf (B,H,W,256) hi ; A3 (p,768)=[hi|hi|lo]
__global__ void k_nchw_split(const float* __restrict__ in, short* __restrict__ feat_bf,
    short* __restrict__ A3){
  __shared__ float tile[32][33];
  int b = blockIdx.z;
  int p0 = blockIdx.x * 32, c0 = blockIdx.y * 32;
  int tx = threadIdx.x, ty = threadIdx.y;
  #pragma unroll
  for (int i = ty; i < 32; i += 8)
    tile[i][tx] = in[((size_t)b*256 + c0 + i)*HWSZ + p0 + tx];
  __syncthreads();
  #pragma unroll
  for (int i = ty; i < 32; i += 8){
    float x = tile[tx][i];
    short hi = f2bf(x);
    short lo = f2bf(x - bf2f(hi));
    size_t p = (size_t)b*HWSZ + p0 + i;
    feat_bf[p*256 + c0 + tx] = hi;
    A3[p*768 + c0 + tx] = hi;
    A3[p*768 + 256 + c0 + tx] = hi;
    A3[p*768 + 512 + c0 + tx] = lo;
  }
}

// 3x3 conv weight (O,C,9) -> bf16 B[n=k*256+o][c] (for tap-major GEMM)
__global__ void k_prep_tapw(const float* __restrict__ w, short* __restrict__ Bm){
  __shared__ short tile[9][256];
  int o = blockIdx.x;
  const float* wo = w + (size_t)o*2304;
  for (int i = threadIdx.x; i < 2304; i += 256){
    int c = i / 9, k = i - c*9;
    tile[k][c] = f2bf(wo[i]);
  }
  __syncthreads();
  for (int i = threadIdx.x; i < 2304; i += 256){
    int k = i >> 8, c = i & 255;
    Bm[((size_t)(k*256 + o))*256 + c] = tile[k][c];
  }
}

// 3x3 conv weight (O,C,9) -> bf16 B2[o][k*256+c] (for implicit-GEMM conv)
__global__ void k_prep_igw(const float* __restrict__ w, short* __restrict__ B2){
  __shared__ short tile[2304];
  int o = blockIdx.x;
  const float* wo = w + (size_t)o*2304;
  for (int i = threadIdx.x; i < 2304; i += 256){
    int c = i / 9, k = i - c*9;
    tile[k*256 + c] = f2bf(wo[i]);
  }
  __syncthreads();
  short* out = B2 + (size_t)o*2304;
  for (int i = threadIdx.x; i < 2304; i += 256) out[i] = tile[i];
}

// ap_w1 (64,256,3,3) -> B3 (640,768) = [Bh|Bl|Bh], rows n=k*64+o, zero-pad n>=576
__global__ void k_prep_apw3(const float* __restrict__ w, short* __restrict__ B3){
  int n = blockIdx.x, c = threadIdx.x;
  short hi = 0, lo = 0;
  if (n < 576){
    int o = n & 63, k = n >> 6;
    float x = w[((size_t)o*256 + c)*9 + k];
    hi = f2bf(x);
    lo = f2bf(x - bf2f(hi));
  }
  B3[(size_t)n*768 + c] = hi;
  B3[(size_t)n*768 + 256 + c] = lo;
  B3[(size_t)n*768 + 512 + c] = hi;
}

__global__ void k_castcopy(const float* __restrict__ in, short* __restrict__ out, int n){
  int i = blockIdx.x*256 + threadIdx.x;
  if (i < n) out[i] = f2bf(in[i]);
}

// ---------------- bf16 TN GEMM v2: reg-dbuf pipeline ----------------
// C[M][*] = A[M][K] x B[N][K]^T. 4 waves 2x2, wave tile (BM/2)x64, block BM x 128.
// EPI: 0 bf16; 1 bf16+bias; 2 bf16 relu+bias; 3 gate; 4 fp32 NCHW +bias; 5 fp32 plain
template<int EPI, int BM>
__global__ __launch_bounds__(256) void k_gemm(const short* __restrict__ A,
    const short* __restrict__ B, void* __restrict__ Cv,
    const float* __restrict__ bias, const short* __restrict__ aux,
    int K, int ldc){
  constexpr int WM = BM/2;
  constexpr int AF = WM/16;
  int w = threadIdx.x >> 6, l = threadIdx.x & 63;
  int wr = w & 1, wc = w >> 1;
  int m0 = blockIdx.x*BM + wr*WM;
  int n0 = blockIdx.y*128 + wc*64;
  int ml = l & 15, g = l >> 4;
  f32x4 acc[AF][4];
  #pragma unroll
  for (int i = 0; i < AF; ++i)
    #pragma unroll
    for (int j = 0; j < 4; ++j) acc[i][j] = (f32x4){0.f,0.f,0.f,0.f};
  const short* Ap = A + (size_t)(m0 + ml)*K + g*8;
  const short* Bp = B + (size_t)(n0 + ml)*K + g*8;
  short8 a0[AF], a1[AF], b0[4], b1[4];
  #pragma unroll
  for (int i = 0; i < AF; ++i) a0[i] = *(const short8*)(Ap + (size_t)(16*i)*K);
  #pragma unroll
  for (int j = 0; j < 4; ++j)  b0[j] = *(const short8*)(Bp + (size_t)(16*j)*K);
  #pragma unroll
  for (int i = 0; i < AF; ++i) a1[i] = *(const short8*)(Ap + (size_t)(16*i)*K + 32);
  #pragma unroll
  for (int j = 0; j < 4; ++j)  b1[j] = *(const short8*)(Bp + (size_t)(16*j)*K + 32);
  for (int k0 = 64; k0 < K; k0 += 64){
    #pragma unroll
    for (int i = 0; i < AF; ++i)
      #pragma unroll
      for (int j = 0; j < 4; ++j)
        acc[i][j] = __builtin_amdgcn_mfma_f32_16x16x32_bf16(a0[i], b0[j], acc[i][j], 0, 0, 0);
    #pragma unroll
    for (int i = 0; i < AF; ++i) a0[i] = *(const short8*)(Ap + (size_t)(16*i)*K + k0);
    #pragma unroll
    for (int j = 0; j < 4; ++j)  b0[j] = *(const short8*)(Bp + (size_t)(16*j)*K + k0);
    #pragma unroll
    for (int i = 0; i < AF; ++i)
      #pragma unroll
      for (int j = 0; j < 4; ++j)
        acc[i][j] = __builtin_amdgcn_mfma_f32_16x16x32_bf16(a1[i], b1[j], acc[i][j], 0, 0, 0);
    #pragma unroll
    for (int i = 0; i < AF; ++i) a1[i] = *(const short8*)(Ap + (size_t)(16*i)*K + k0 + 32);
    #pragma unroll
    for (int j = 0; j < 4; ++j)  b1[j] = *(const short8*)(Bp + (size_t)(16*j)*K + k0 + 32);
  }
  #pragma unroll
  for (int i = 0; i < AF; ++i)
    #pragma unroll
    for (int j = 0; j < 4; ++j)
      acc[i][j] = __builtin_amdgcn_mfma_f32_16x16x32_bf16(a0[i], b0[j], acc[i][j], 0, 0, 0);
  #pragma unroll
  for (int i = 0; i < AF; ++i)
    #pragma unroll
    for (int j = 0; j < 4; ++j)
      acc[i][j] = __builtin_amdgcn_mfma_f32_16x16x32_bf16(a1[i], b1[j], acc[i][j], 0, 0, 0);

  if constexpr (EPI == 4){
    // stage through LDS, store NCHW coalesced (BM==64 expected)
    __shared__ float cst[BM][129];
    #pragma unroll
    for (int fm = 0; fm < AF; ++fm)
      #pragma unroll
      for (int fn = 0; fn < 4; ++fn)
        #pragma unroll
        for (int r = 0; r < 4; ++r){
          int cl = wc*64 + fn*16 + ml;
          cst[wr*WM + fm*16 + g*4 + r][cl] = acc[fm][fn][r] + bias[blockIdx.y*128 + cl];
        }
    __syncthreads();
    int px0 = blockIdx.x*BM;
    int b = px0 >> 12, hw0 = px0 & 4095;
    int o = threadIdx.x >> 1, seg = (threadIdx.x & 1)*(BM/2);
    float* op = (float*)Cv + (((size_t)(b*256 + blockIdx.y*128 + o)) << 12) + hw0 + seg;
    #pragma unroll
    for (int i = 0; i < BM/2; i += 4){
      float4 vv = {cst[seg+i][o], cst[seg+i+1][o], cst[seg+i+2][o], cst[seg+i+3][o]};
      *(float4*)(op + i) = vv;
    }
  } else {
    #pragma unroll
    for (int fm = 0; fm < AF; ++fm)
      #pragma unroll
      for (int fn = 0; fn < 4; ++fn)
        #pragma unroll
        for (int r = 0; r < 4; ++r){
          int row = m0 + fm*16 + g*4 + r;
          int col = n0 + fn*16 + ml;
          float v = acc[fm][fn][r];
          if constexpr (EPI == 0){
            ((short*)Cv)[(size_t)row*ldc + col] = f2bf(v);
          } else if constexpr (EPI == 1){
            ((short*)Cv)[(size_t)row*ldc + col] = f2bf(v + bias[col]);
          } else if constexpr (EPI == 2){
            ((short*)Cv)[(size_t)row*ldc + col] = f2bf(fmaxf(v + bias[col], 0.f));
          } else if constexpr (EPI == 3){
            float f = bf2f(aux[(size_t)row*320 + col]);
            float s = 1.f/(1.f + __expf(-(v + bias[col])));
            ((short*)Cv)[(size_t)row*ldc + col] = f2bf(f * (1.f + s));
          } else {
            ((float*)Cv)[(size_t)row*ldc + col] = v;
          }
        }
  }
}

// ---------------- implicit-GEMM 3x3 conv: t[p][o] = b[o] + sum enh[p+d][c] w[o][c][k] ----
// M=8192 (tile 64), N=256 (tile 128), K=2304. X bf16 NHWC, B2 [o][k*256+c], t fp32 NHWC.
__global__ __launch_bounds__(256) void k_igconv(const short* __restrict__ X,
    const short* __restrict__ B2, const float* __restrict__ bias,
    float* __restrict__ t){
  int w = threadIdx.x >> 6, l = threadIdx.x & 63;
  int wr = w & 1, wc = w >> 1;
  int m0 = blockIdx.x*64 + wr*32;
  int n0 = blockIdx.y*128 + wc*64;
  int ml = l & 15, g = l >> 4;
  f32x4 acc[2][4];
  #pragma unroll
  for (int i = 0; i < 2; ++i)
    #pragma unroll
    for (int j = 0; j < 4; ++j) acc[i][j] = (f32x4){0.f,0.f,0.f,0.f};
  int p0 = m0 + ml, p1 = m0 + 16 + ml;
  int y0 = (p0 >> 6) & 63, x0 = p0 & 63;
  int y1 = (p1 >> 6) & 63, x1 = p1 & 63;
  const short* Bp = B2 + (size_t)(n0 + ml)*2304 + g*8;
  const short8 zz = (short8){0,0,0,0,0,0,0,0};

  #define LOADA(dst, k0v) { \
    int tap = (k0v) >> 8; \
    int t3 = tap/3; \
    int dy = t3 - 1, dx = tap - t3*3 - 1; \
    int cofs = ((k0v) & 255) + g*8; \
    int shift = dy*64 + dx; \
    bool v0 = ((unsigned)(y0+dy) < 64u) && ((unsigned)(x0+dx) < 64u); \
    bool v1 = ((unsigned)(y1+dy) < 64u) && ((unsigned)(x1+dx) < 64u); \
    dst[0] = v0 ? *(const short8*)(X + ((size_t)(p0 + shift)*256 + cofs)) : zz; \
    dst[1] = v1 ? *(const short8*)(X + ((size_t)(p1 + shift)*256 + cofs)) : zz; \
  }
  #define LOADB(dst, k0v) { \
    _Pragma("unroll") \
    for (int j = 0; j < 4; ++j) dst[j] = *(const short8*)(Bp + (size_t)(16*j)*2304 + (k0v)); \
  }
  #define MFMAS(aa, bb) { \
    _Pragma("unroll") \
    for (int i = 0; i < 2; ++i) \
      _Pragma("unroll") \
      for (int j = 0; j < 4; ++j) \
        acc[i][j] = __builtin_amdgcn_mfma_f32_16x16x32_bf16(aa[i], bb[j], acc[i][j], 0, 0, 0); \
  }

  short8 a0[2], a1[2], b0[4], b1[4];
  LOADA(a0, 0) LOADB(b0, 0)
  LOADA(a1, 32) LOADB(b1, 32)
  for (int k0 = 64; k0 < 2304; k0 += 64){
    MFMAS(a0, b0)
    LOADA(a0, k0) LOADB(b0, k0)
    MFMAS(a1, b1)
    LOADA(a1, k0+32) LOADB(b1, k0+32)
  }
  MFMAS(a0, b0)
  MFMAS(a1, b1)
  #undef LOADA
  #undef LOADB
  #undef MFMAS

  #pragma unroll
  for (int fm = 0; fm < 2; ++fm)
    #pragma unroll
    for (int fn = 0; fn < 4; ++fn)
      #pragma unroll
      for (int r = 0; r < 4; ++r){
        int row = m0 + fm*16 + g*4 + r;
        int col = n0 + fn*16 + ml;
        t[(size_t)row*256 + col] = acc[fm][fn][r] + bias[col];
      }
}

// ---------------- angle head: tap-sum + relu + 64->1 proj ----------------
__global__ void k_aph1(const float* __restrict__ T, const float* __restrict__ b1,
    const float* __restrict__ w2, const float* __restrict__ b2,
    float* __restrict__ ang){
  const int KYi[9] = {-1,-1,-1,0,0,0,1,1,1};
  const int KXi[9] = {-1,0,1,-1,0,1,-1,0,1};
  int o = threadIdx.x & 63;
  int p = blockIdx.x*4 + (threadIdx.x >> 6);
  int hw = p & 4095;
  int h = hw >> 6, w = hw & 63;
  float acc = b1[o];
  #pragma unroll
  for (int k = 0; k < 9; ++k){
    int y = h + KYi[k], x = w + KXi[k];
    if (y < 0 || y > 63 || x < 0 || x > 63) continue;
    acc += T[(size_t)(p + KYi[k]*64 + KXi[k])*640 + k*64 + o];
  }
  float v = fmaxf(acc, 0.f) * w2[o];
  float s = wsum64(v);
  if (o == 0) ang[p] = s + b2[0];
}

// ---------------- 2) angle encoding -> gateA cols 256..319 (bf16) ----------------
__global__ void k_angle_encode(const float* __restrict__ ang, const float* __restrict__ freq,
    const float* __restrict__ w1, const float* __restrict__ b1,
    const float* __restrict__ lng, const float* __restrict__ lnb,
    const float* __restrict__ w2, const float* __restrict__ b2,
    short* __restrict__ gateA){
  int lane = threadIdx.x & 63;
  int p = blockIdx.x * 4 + (threadIdx.x >> 6);
  float an = ang[p] * (2.0f / PI_F);
  int f = lane & 31;
  float ph = an * freq[f] * ((float)f * (PI_F / 32.0f));
  float emb = (lane < 32) ? __sinf(ph) : __cosf(ph);
  float h = b1[lane];
  const float* w1r = w1 + lane*64;
  #pragma unroll 8
  for (int i = 0; i < 64; ++i){
    float e = __shfl(emb, i, 64);
    h = fmaf(e, w1r[i], h);
  }
  float mu = wsum64(h) * (1.0f/64.0f);
  float d = h - mu;
  float var = wsum64(d*d) * (1.0f/64.0f);
  float hn = fmaf(d * rsqrtf(var + 1e-5f), lng[lane], lnb[lane]);
  float r = fmaxf(hn, 0.f);
  float o = b2[lane];
  const float* w2r = w2 + lane*64;
  #pragma unroll 8
  for (int i = 0; i < 64; ++i){
    float e = __shfl(r, i, 64);
    o = fmaf(e, w2r[i], o);
  }
  gateA[(size_t)p*320 + 256 + lane] = f2bf(o);
}

// ---------------- 3/4) bilinear gather on G: 4 px/block, 3 hyps, ushort4, XCD bands --------
__global__ __launch_bounds__(256) void k_sample(const short* __restrict__ G,
    const float* __restrict__ ang, const float* __restrict__ bias,
    short* __restrict__ cand){
  const float KYc[9] = {-1,-1,-1,0,0,0,1,1,1};
  const float KXc[9] = {-1,0,1,-1,0,1,-1,0,1};
  int id = blockIdx.x;                       // 2048 blocks
  int sw = (id & 7) * 256 + (id >> 3);       // bijective XCD band swizzle
  int p = sw * 4 + (threadIdx.x >> 6);
  int lane = threadIdx.x & 63;
  int c4 = lane * 4;
  int b = p >> 12, hw = p & 4095;
  int h = hw >> 6, w = hw & 63;
  float fh = (float)h, fw = (float)w;
  float a0 = ang[p];
  float4 bs = *(const float4*)(bias + c4);
  float acc[3][4];
  #pragma unroll
  for (int i = 0; i < 3; ++i){
    acc[i][0] = bs.x; acc[i][1] = bs.y; acc[i][2] = bs.z; acc[i][3] = bs.w;
  }
  const short* Gb = G + (size_t)b*HWSZ*2304 + c4;
  #pragma unroll 1
  for (int hyp = 0; hyp < 3; ++hyp){
    float a = a0 + ((float)hyp - 1.0f) * (PI_F / 12.0f);
    float sn = __sinf(a), cs = __cosf(a);
    #pragma unroll
    for (int k = 0; k < 9; ++k){
      float py = fh + KXc[k]*sn + KYc[k]*cs;
      float px = fw + KXc[k]*cs - KYc[k]*sn;
      float y0f = floorf(py), x0f = floorf(px);
      float wy = py - y0f, wx = px - x0f;
      int y0 = (int)y0f, x0 = (int)x0f;
      const short* Gk = Gb + k*256;
      #pragma unroll
      for (int dy = 0; dy < 2; ++dy){
        int yy = y0 + dy;
        if (yy < 0 || yy > 63) continue;
        float fy = dy ? wy : 1.f - wy;
        #pragma unroll
        for (int dx = 0; dx < 2; ++dx){
          int xx = x0 + dx;
          if (xx < 0 || xx > 63) continue;
          float fxy = fy * (dx ? wx : 1.f - wx);
          short4_t v = *(const short4_t*)(Gk + (size_t)(yy*64 + xx)*2304);
          acc[hyp][0] = fmaf(fxy, bf2f(v[0]), acc[hyp][0]);
          acc[hyp][1] = fmaf(fxy, bf2f(v[1]), acc[hyp][1]);
          acc[hyp][2] = fmaf(fxy, bf2f(v[2]), acc[hyp][2]);
          acc[hyp][3] = fmaf(fxy, bf2f(v[3]), acc[hyp][3]);
        }
      }
    }
  }
  #pragma unroll
  for (int hyp = 0; hyp < 3; ++hyp){
    short4_t o;
    #pragma unroll
    for (int j = 0; j < 4; ++j) o[j] = f2bf(acc[hyp][j]);
    *(short4_t*)(cand + ((size_t)hyp*NPIX + p)*256 + c4) = o;
  }
}

// ---------------- 4) attention core: Q (8192,256), KV (24576,512) -> O bf16 ----------------
__global__ void k_attn(const short* __restrict__ Q, const short* __restrict__ KV,
    short* __restrict__ O){
  int lane = threadIdx.x & 63;
  int p = blockIdx.x*4 + (threadIdx.x >> 6);
  float q[4];
  { short4_t t = *(const short4_t*)(Q + (size_t)p*256 + lane*4);
    #pragma unroll
    for (int j = 0; j < 4; ++j) q[j] = bf2f(t[j]); }
  float kv[3][2][4];
  #pragma unroll
  for (int i = 0; i < 3; ++i){
    const short* rp = KV + (size_t)(i*NPIX + p)*512 + lane*4;
    short4_t kt = *(const short4_t*)rp;
    short4_t vt = *(const short4_t*)(rp + 256);
    #pragma unroll
    for (int j = 0; j < 4; ++j){ kv[i][0][j] = bf2f(kt[j]); kv[i][1][j] = bf2f(vt[j]); }
  }
  const float sc = 0.17677669529663688f; // 1/sqrt(32)
  float s[3];
  #pragma unroll
  for (int i = 0; i < 3; ++i){
    float d = 0.f;
    #pragma unroll
    for (int j = 0; j < 4; ++j) d = fmaf(q[j], kv[i][0][j], d);
    s[i] = wsum8(d) * sc;
  }
  float m = fmaxf(s[0], fmaxf(s[1], s[2]));
  float e0 = __expf(s[0]-m), e1 = __expf(s[1]-m), e2 = __expf(s[2]-m);
  float inv = 1.f/(e0+e1+e2);
  short4_t ot;
  #pragma unroll
  for (int j = 0; j < 4; ++j)
    ot[j] = f2bf((e0*kv[0][1][j] + e1*kv[1][1][j] + e2*kv[2][1][j]) * inv);
  *(short4_t*)(O + (size_t)p*256 + lane*4) = ot;
}

// ---------------- 6b) group-norm stats ----------------
__global__ void k_gnstat(const float* __restrict__ t, float* __restrict__ stat){
  int bg = blockIdx.x;
  int b = bg >> 5, g = bg & 31;
  const float* base = t + (size_t)b*HWSZ*256 + g*8;
  float s = 0.f, s2 = 0.f;
  for (int idx = threadIdx.x; idx < 8*HWSZ; idx += 256){
    int p = idx >> 3, cc = idx & 7;
    float v = base[(size_t)p*256 + cc];
    s += v; s2 = fmaf(v, v, s2);
  }
  s = wsum64(s); s2 = wsum64(s2);
  __shared__ float rs[4], rs2[4];
  int wid = threadIdx.x >> 6;
  if ((threadIdx.x & 63) == 0){ rs[wid] = s; rs2[wid] = s2; }
  __syncthreads();
  if (threadIdx.x == 0){
    float S = rs[0]+rs[1]+rs[2]+rs[3];
    float S2 = rs2[0]+rs2[1]+rs2[2]+rs2[3];
    float mean = S * (1.f/32768.f);
    float var = S2 * (1.f/32768.f) - mean*mean;
    stat[bg*2]   = mean;
    stat[bg*2+1] = rsqrtf(var + 1e-5f);
  }
}

// ---------------- 6c) GN + relu -> bf16 ----------------
__global__ void k_gnrelu(const float* __restrict__ t, const float* __restrict__ stat,
    const float* __restrict__ gng, const float* __restrict__ gnb,
    short* __restrict__ a){
  int p = blockIdx.x, c = threadIdx.x;
  int b = p >> 12, g = c >> 3;
  float mean = stat[(b*32+g)*2], rstd = stat[(b*32+g)*2+1];
  float gg = gng[c] * rstd;
  float bb = gnb[c] - mean*gg;
  float v = t[(size_t)p*256 + c];
  a[(size_t)p*256 + c] = f2bf(fmaxf(fmaf(v, gg, bb), 0.f));
}

// ---------------- launch ----------------
extern "C" void kernel_launch(void* const* d_in, const int* in_sizes, int n_in,
                              void* d_out, int out_size, void* d_ws, size_t ws_size,
                              hipStream_t stream){
  (void)in_sizes; (void)n_in; (void)out_size; (void)ws_size;
  const float* features   = (const float*)d_in[0];
  const float* ap_w1      = (const float*)d_in[1];
  const float* ap_b1      = (const float*)d_in[2];
  const float* ap_w2      = (const float*)d_in[3];
  const float* ap_b2      = (const float*)d_in[4];
  const float* freq       = (const float*)d_in[5];
  const float* ae_w1      = (const float*)d_in[6];
  const float* ae_b1      = (const float*)d_in[7];
  const float* ae_ln_g    = (const float*)d_in[8];
  const float* ae_ln_b    = (const float*)d_in[9];
  const float* ae_w2      = (const float*)d_in[10];
  const float* ae_b2      = (const float*)d_in[11];
  const float* dc_w       = (const float*)d_in[12];
  const float* dc_b       = (const float*)d_in[13];
  const float* attn_in_w  = (const float*)d_in[14];
  const float* attn_in_b  = (const float*)d_in[15];
  const float* attn_out_w = (const float*)d_in[16];
  const float* attn_out_b = (const float*)d_in[17];
  const float* ja_w1      = (const float*)d_in[18];
  const float* ja_b1      = (const float*)d_in[19];
  const float* ja_w2      = (const float*)d_in[20];
  const float* ja_b2      = (const float*)d_in[21];
  const float* op_w1      = (const float*)d_in[22];
  const float* op_b1      = (const float*)d_in[23];
  const float* gn_g       = (const float*)d_in[24];
  const float* gn_b       = (const float*)d_in[25];
  const float* op_w2      = (const float*)d_in[26];
  const float* op_b2      = (const float*)d_in[27];

  char* base = (char*)d_ws;
  #define ALLOC(ty, name, elems) ty* name = (ty*)base; base += (size_t)(elems)*sizeof(ty);
  ALLOC(short, feat_bf, 8192*256)
  ALLOC(short, Bdc,     2304*256)
  ALLOC(short, B2op,    256*2304)
  ALLOC(short, B3ap,    640*768)
  ALLOC(short, inw_bf,  768*256)
  ALLOC(short, wot_bf,  256*256)
  ALLOC(short, jw1_bf,  256*320)
  ALLOC(short, jw2_bf,  256*256)
  ALLOC(short, wop2_bf, 256*256)
  ALLOC(short, Gbuf,    24576*768)   // serves: T_ap(fp32) -> G -> KV/Q
  ALLOC(short, cand_bf, 3*8192*256)  // aliased as A3 (8192x768) before sampling
  ALLOC(short, O_bf,    8192*256)
  ALLOC(short, gateA,   8192*320)
  ALLOC(short, hid_bf,  8192*256)
  ALLOC(short, enh_bf,  8192*256)
  ALLOC(float, angbuf,  8192)
  ALLOC(float, tbuf,    8192*256)
  ALLOC(float, gstat,   128)
  ALLOC(short, a_bf,    8192*256)
  #undef ALLOC
  short* A3 = cand_bf;                      // 8192*768, dead before cand written
  float* T_ap = (float*)Gbuf;               // 8192*640 fp32
  short* KVbuf = Gbuf;                      // 24576*512 bf16
  short* Qbuf  = Gbuf + (size_t)24576*512;  // 8192*256 bf16

  dim3 t32(32, 8);
  k_nchw_split<<<dim3(128,8,2), t32, 0, stream>>>(features, feat_bf, A3);
  k_prep_tapw<<<256, 256, 0, stream>>>(dc_w,  Bdc);
  k_prep_igw<<<256, 256, 0, stream>>>(op_w1, B2op);
  k_prep_apw3<<<640, 256, 0, stream>>>(ap_w1, B3ap);
  k_castcopy<<<768, 256, 0, stream>>>(attn_in_w,  inw_bf,  768*256);
  k_castcopy<<<256, 256, 0, stream>>>(attn_out_w, wot_bf,  256*256);
  k_castcopy<<<320, 256, 0, stream>>>(ja_w1,      jw1_bf,  256*320);
  k_castcopy<<<256, 256, 0, stream>>>(ja_w2,      jw2_bf,  256*256);
  k_castcopy<<<256, 256, 0, stream>>>(op_w2,      wop2_bf, 256*256);

  // angle head: T = A3 x B3ap^T (compensated bf16, fp32 out)
  k_gemm<5,128><<<dim3(64,5), 256, 0, stream>>>(A3, B3ap, T_ap, nullptr, nullptr, 768, 640);
  k_aph1<<<2048, 256, 0, stream>>>(T_ap, ap_b1, ap_w2, ap_b2, angbuf);
  k_angle_encode<<<2048, 256, 0, stream>>>(angbuf, freq, ae_w1, ae_b1, ae_ln_g, ae_ln_b,
                                           ae_w2, ae_b2, gateA);
  // G = feat x Bdc^T (8192,2304) ; sample -> cand
  k_gemm<0,128><<<dim3(64,18), 256, 0, stream>>>(feat_bf, Bdc, Gbuf, nullptr, nullptr, 256, 2304);
  k_sample<<<2048, 256, 0, stream>>>(Gbuf, angbuf, dc_b, cand_bf);
  // KV = cand x in_w[256:768]^T + inb[256:768]  (24576,512)
  k_gemm<1,128><<<dim3(192,4), 256, 0, stream>>>(cand_bf, inw_bf + (size_t)256*256, KVbuf,
                                                 attn_in_b + 256, nullptr, 256, 512);
  // Q = cand[hyp1] x in_w[0:256]^T + inb[0:256]  (8192,256)
  k_gemm<1,64><<<dim3(128,2), 256, 0, stream>>>(cand_bf + (size_t)NPIX*256, inw_bf, Qbuf,
                                                attn_in_b, nullptr, 256, 256);
  k_attn<<<2048, 256, 0, stream>>>(Qbuf, KVbuf, O_bf);
  // fused = O x out_w^T + outb -> gateA cols 0..255
  k_gemm<1,64><<<dim3(128,2), 256, 0, stream>>>(O_bf, wot_bf, gateA, attn_out_b, nullptr, 256, 320);
  // hid = relu(gateA x ja_w1^T + b1)
  k_gemm<2,64><<<dim3(128,2), 256, 0, stream>>>(gateA, jw1_bf, hid_bf, ja_b1, nullptr, 320, 256);
  // enh = fused * (1 + sigmoid(hid x ja_w2^T + b2))
  k_gemm<3,64><<<dim3(128,2), 256, 0, stream>>>(hid_bf, jw2_bf, enh_bf, ja_b2, gateA, 256, 256);
  // t = conv3x3(enh, op_w1) + op_b1   (implicit GEMM, fused shift-add)
  k_igconv<<<dim3(128,2), 256, 0, stream>>>(enh_bf, B2op, op_b1, tbuf);
  k_gnstat<<<64, 256, 0, stream>>>(tbuf, gstat);
  k_gnrelu<<<NPIX, 256, 0, stream>>>(tbuf, gstat, gn_g, gn_b, a_bf);
  // out = GNrelu x op_w2^T + b2, NCHW fp32
  k_gemm<4,64><<<dim3(128,2), 256, 0, stream>>>(a_bf, wop2_bf, (float*)d_out, op_b2, nullptr, 256, 256);
}

// Round 6
// 389.430 us; speedup vs baseline: 6.6371x; 1.0155x over previous
//
#include <hip/hip_runtime.h>

#define PI_F 3.14159265358979323846f
#define HWSZ 4096   // H*W
#define NPIX 8192   // B*H*W

typedef __attribute__((ext_vector_type(8))) short short8;
typedef __attribute__((ext_vector_type(4))) short short4_t;
typedef __attribute__((ext_vector_type(4))) float f32x4;

__device__ __forceinline__ short f2bf(float x){
  unsigned u = __float_as_uint(x);
  unsigned r = (u + 0x7FFFu + ((u >> 16) & 1u)) >> 16;
  return (short)r;
}
__device__ __forceinline__ float bf2f(short v){
  return __uint_as_float(((unsigned)(unsigned short)v) << 16);
}

__device__ __forceinline__ float wsum64(float v){
  #pragma unroll
  for (int m = 32; m >= 1; m >>= 1) v += __shfl_xor(v, m, 64);
  return v;
}
__device__ __forceinline__ float wsum8(float v){
  v += __shfl_xor(v, 1, 64);
  v += __shfl_xor(v, 2, 64);
  v += __shfl_xor(v, 4, 64);
  return v;
}

// ---------------- prep kernels ----------------
__global__ void k_zero4(short* __restrict__ p, int n4){
  int i = blockIdx.x*256 + threadIdx.x;
  if (i < n4) ((short4_t*)p)[i] = (short4_t){0,0,0,0};
}

// features (B,256,H,W) -> feat_bf (B,H,W,256) hi ; A3 (p,768)=[hi|hi|lo]
__global__ void k_nchw_split(const float* __restrict__ in, short* __restrict__ feat_bf,
    short* __restrict__ A3){
  __shared__ float tile[32][33];
  int b = blockIdx.z;
  int p0 = blockIdx.x * 32, c0 = blockIdx.y * 32;
  int tx = threadIdx.x, ty = threadIdx.y;
  #pragma unroll
  for (int i = ty; i < 32; i += 8)
    tile[i][tx] = in[((size_t)b*256 + c0 + i)*HWSZ + p0 + tx];
  __syncthreads();
  #pragma unroll
  for (int i = ty; i < 32; i += 8){
    float x = tile[tx][i];
    short hi = f2bf(x);
    short lo = f2bf(x - bf2f(hi));
    size_t p = (size_t)b*HWSZ + p0 + i;
    feat_bf[p*256 + c0 + tx] = hi;
    A3[p*768 + c0 + tx] = hi;
    A3[p*768 + 256 + c0 + tx] = hi;
    A3[p*768 + 512 + c0 + tx] = lo;
  }
}

// 3x3 conv weight (O,C,9) -> bf16 B[n=k*256+o][c] (tap-major GEMM B)
__global__ void k_prep_tapw(const float* __restrict__ w, short* __restrict__ Bm){
  __shared__ short tile[9][256];
  int o = blockIdx.x;
  const float* wo = w + (size_t)o*2304;
  for (int i = threadIdx.x; i < 2304; i += 256){
    int c = i / 9, k = i - c*9;
    tile[k][c] = f2bf(wo[i]);
  }
  __syncthreads();
  for (int i = threadIdx.x; i < 2304; i += 256){
    int k = i >> 8, c = i & 255;
    Bm[((size_t)(k*256 + o))*256 + c] = tile[k][c];
  }
}

// 3x3 conv weight (O,C,9) -> bf16 B2[o][k*256+c] (implicit-GEMM conv B)
__global__ void k_prep_igw(const float* __restrict__ w, short* __restrict__ B2){
  __shared__ short tile[2304];
  int o = blockIdx.x;
  const float* wo = w + (size_t)o*2304;
  for (int i = threadIdx.x; i < 2304; i += 256){
    int c = i / 9, k = i - c*9;
    tile[k*256 + c] = f2bf(wo[i]);
  }
  __syncthreads();
  short* out = B2 + (size_t)o*2304;
  for (int i = threadIdx.x; i < 2304; i += 256) out[i] = tile[i];
}

// ap_w1 (64,256,3,3) -> B3 (640,768) = [Bh|Bl|Bh], rows n=k*64+o, zero-pad n>=576
__global__ void k_prep_apw3(const float* __restrict__ w, short* __restrict__ B3){
  int n = blockIdx.x, c = threadIdx.x;
  short hi = 0, lo = 0;
  if (n < 576){
    int o = n & 63, k = n >> 6;
    float x = w[((size_t)o*256 + c)*9 + k];
    hi = f2bf(x);
    lo = f2bf(x - bf2f(hi));
  }
  B3[(size_t)n*768 + c] = hi;
  B3[(size_t)n*768 + 256 + c] = lo;
  B3[(size_t)n*768 + 512 + c] = hi;
}

// all 5 small weights cast in one launch
__global__ void k_castall(const float* __restrict__ s0, const float* __restrict__ s1,
    const float* __restrict__ s2, const float* __restrict__ s3, const float* __restrict__ s4,
    short* __restrict__ d0, short* __restrict__ d1, short* __restrict__ d2,
    short* __restrict__ d3, short* __restrict__ d4){
  int i = blockIdx.x*256 + threadIdx.x;
  if (i < 196608) d0[i] = f2bf(s0[i]);
  else if (i < 262144) d1[i-196608] = f2bf(s1[i-196608]);
  else if (i < 344064) d2[i-262144] = f2bf(s2[i-262144]);
  else if (i < 409600) d3[i-344064] = f2bf(s3[i-344064]);
  else if (i < 475136) d4[i-409600] = f2bf(s4[i-409600]);
}

// ---------------- bf16 TN GEMM: reg-dbuf pipeline ----------------
// C[M][*] = A[M][K] x B[N][K]^T. 4 waves 2x2, wave tile (BM/2)x64, block BM x 128.
// EPI: 0 bf16; 1 bf16+bias; 2 bf16 relu+bias; 3 gate->linear; 4 fp32 NCHW +bias;
//      5 fp32 plain; 6 gate->padded NHWC
template<int EPI, int BM>
__global__ __launch_bounds__(256) void k_gemm(const short* __restrict__ A,
    const short* __restrict__ B, void* __restrict__ Cv,
    const float* __restrict__ bias, const short* __restrict__ aux,
    int K, int ldc){
  constexpr int WM = BM/2;
  constexpr int AF = WM/16;
  int w = threadIdx.x >> 6, l = threadIdx.x & 63;
  int wr = w & 1, wc = w >> 1;
  int m0 = blockIdx.x*BM + wr*WM;
  int n0 = blockIdx.y*128 + wc*64;
  int ml = l & 15, g = l >> 4;
  f32x4 acc[AF][4];
  #pragma unroll
  for (int i = 0; i < AF; ++i)
    #pragma unroll
    for (int j = 0; j < 4; ++j) acc[i][j] = (f32x4){0.f,0.f,0.f,0.f};
  const short* Ap = A + (size_t)(m0 + ml)*K + g*8;
  const short* Bp = B + (size_t)(n0 + ml)*K + g*8;
  short8 a0[AF], a1[AF], b0[4], b1[4];
  #pragma unroll
  for (int i = 0; i < AF; ++i) a0[i] = *(const short8*)(Ap + (size_t)(16*i)*K);
  #pragma unroll
  for (int j = 0; j < 4; ++j)  b0[j] = *(const short8*)(Bp + (size_t)(16*j)*K);
  #pragma unroll
  for (int i = 0; i < AF; ++i) a1[i] = *(const short8*)(Ap + (size_t)(16*i)*K + 32);
  #pragma unroll
  for (int j = 0; j < 4; ++j)  b1[j] = *(const short8*)(Bp + (size_t)(16*j)*K + 32);
  for (int k0 = 64; k0 < K; k0 += 64){
    #pragma unroll
    for (int i = 0; i < AF; ++i)
      #pragma unroll
      for (int j = 0; j < 4; ++j)
        acc[i][j] = __builtin_amdgcn_mfma_f32_16x16x32_bf16(a0[i], b0[j], acc[i][j], 0, 0, 0);
    #pragma unroll
    for (int i = 0; i < AF; ++i) a0[i] = *(const short8*)(Ap + (size_t)(16*i)*K + k0);
    #pragma unroll
    for (int j = 0; j < 4; ++j)  b0[j] = *(const short8*)(Bp + (size_t)(16*j)*K + k0);
    #pragma unroll
    for (int i = 0; i < AF; ++i)
      #pragma unroll
      for (int j = 0; j < 4; ++j)
        acc[i][j] = __builtin_amdgcn_mfma_f32_16x16x32_bf16(a1[i], b1[j], acc[i][j], 0, 0, 0);
    #pragma unroll
    for (int i = 0; i < AF; ++i) a1[i] = *(const short8*)(Ap + (size_t)(16*i)*K + k0 + 32);
    #pragma unroll
    for (int j = 0; j < 4; ++j)  b1[j] = *(const short8*)(Bp + (size_t)(16*j)*K + k0 + 32);
  }
  #pragma unroll
  for (int i = 0; i < AF; ++i)
    #pragma unroll
    for (int j = 0; j < 4; ++j)
      acc[i][j] = __builtin_amdgcn_mfma_f32_16x16x32_bf16(a0[i], b0[j], acc[i][j], 0, 0, 0);
  #pragma unroll
  for (int i = 0; i < AF; ++i)
    #pragma unroll
    for (int j = 0; j < 4; ++j)
      acc[i][j] = __builtin_amdgcn_mfma_f32_16x16x32_bf16(a1[i], b1[j], acc[i][j], 0, 0, 0);

  if constexpr (EPI == 4){
    __shared__ float cst[BM][129];
    #pragma unroll
    for (int fm = 0; fm < AF; ++fm)
      #pragma unroll
      for (int fn = 0; fn < 4; ++fn)
        #pragma unroll
        for (int r = 0; r < 4; ++r){
          int cl = wc*64 + fn*16 + ml;
          cst[wr*WM + fm*16 + g*4 + r][cl] = acc[fm][fn][r] + bias[blockIdx.y*128 + cl];
        }
    __syncthreads();
    int px0 = blockIdx.x*BM;
    int b = px0 >> 12, hw0 = px0 & 4095;
    int o = threadIdx.x >> 1, seg = (threadIdx.x & 1)*(BM/2);
    float* op = (float*)Cv + (((size_t)(b*256 + blockIdx.y*128 + o)) << 12) + hw0 + seg;
    #pragma unroll
    for (int i = 0; i < BM/2; i += 4){
      float4 vv = {cst[seg+i][o], cst[seg+i+1][o], cst[seg+i+2][o], cst[seg+i+3][o]};
      *(float4*)(op + i) = vv;
    }
  } else {
    #pragma unroll
    for (int fm = 0; fm < AF; ++fm)
      #pragma unroll
      for (int fn = 0; fn < 4; ++fn)
        #pragma unroll
        for (int r = 0; r < 4; ++r){
          int row = m0 + fm*16 + g*4 + r;
          int col = n0 + fn*16 + ml;
          float v = acc[fm][fn][r];
          if constexpr (EPI == 0){
            ((short*)Cv)[(size_t)row*ldc + col] = f2bf(v);
          } else if constexpr (EPI == 1){
            ((short*)Cv)[(size_t)row*ldc + col] = f2bf(v + bias[col]);
          } else if constexpr (EPI == 2){
            ((short*)Cv)[(size_t)row*ldc + col] = f2bf(fmaxf(v + bias[col], 0.f));
          } else if constexpr (EPI == 3){
            float f = bf2f(aux[(size_t)row*320 + col]);
            float s = 1.f/(1.f + __expf(-(v + bias[col])));
            ((short*)Cv)[(size_t)row*ldc + col] = f2bf(f * (1.f + s));
          } else if constexpr (EPI == 6){
            float f = bf2f(aux[(size_t)row*320 + col]);
            float s = 1.f/(1.f + __expf(-(v + bias[col])));
            int b = row >> 12, hw = row & 4095;
            int pi = b*4356 + ((hw>>6)+1)*66 + (hw&63) + 1;
            ((short*)Cv)[(size_t)pi*256 + col] = f2bf(f * (1.f + s));
          } else {
            ((float*)Cv)[(size_t)row*ldc + col] = v;
          }
        }
  }
}

// ---------------- implicit-GEMM 3x3 conv on PADDED input, split-K by tap group ----
// grid (128, 2, 3). PG[z][p][o] = sum over taps 3z..3z+2. Xpad: (B,66,66,256) bf16.
__global__ __launch_bounds__(256) void k_igconv(const short* __restrict__ Xpad,
    const short* __restrict__ B2, float* __restrict__ PG){
  int zg = blockIdx.z;
  int w = threadIdx.x >> 6, l = threadIdx.x & 63;
  int wr = w & 1, wc = w >> 1;
  int m0 = blockIdx.x*64 + wr*32;     // 64-px tile = one image row
  int n0 = blockIdx.y*128 + wc*64;
  int ml = l & 15, g = l >> 4;
  f32x4 acc[2][4];
  #pragma unroll
  for (int i = 0; i < 2; ++i)
    #pragma unroll
    for (int j = 0; j < 4; ++j) acc[i][j] = (f32x4){0.f,0.f,0.f,0.f};
  int p0 = m0 + ml;
  int b = p0 >> 12, hw = p0 & 4095;
  int q0 = b*4356 + ((hw>>6)+1)*66 + (hw&63) + 1;  // padded index; q1 = q0+16
  const short* Bp = B2 + (size_t)(n0 + ml)*2304 + zg*768 + g*8;
  int toff[3];
  #pragma unroll
  for (int i = 0; i < 3; ++i){
    int t = zg*3 + i;
    toff[i] = (t/3 - 1)*66 + (t%3 - 1);
  }
  #define LA(dst, j) { int tap = (j) >> 3, cc = ((j) & 7)*32; \
    const short* ap = Xpad + (size_t)(q0 + toff[tap])*256 + cc + g*8; \
    dst[0] = *(const short8*)ap; \
    dst[1] = *(const short8*)(ap + 4096); }
  #define LB(dst, j) { \
    _Pragma("unroll") \
    for (int jj = 0; jj < 4; ++jj) dst[jj] = *(const short8*)(Bp + (size_t)(16*jj)*2304 + (j)*32); }
  #define MFMAS(aa, bb) { \
    _Pragma("unroll") \
    for (int i = 0; i < 2; ++i) \
      _Pragma("unroll") \
      for (int j = 0; j < 4; ++j) \
        acc[i][j] = __builtin_amdgcn_mfma_f32_16x16x32_bf16(aa[i], bb[j], acc[i][j], 0, 0, 0); }

  short8 a0[2], a1[2], b0[4], b1[4];
  LA(a0, 0) LB(b0, 0)
  LA(a1, 1) LB(b1, 1)
  for (int j = 2; j < 24; j += 2){
    MFMAS(a0, b0)
    LA(a0, j) LB(b0, j)
    MFMAS(a1, b1)
    LA(a1, j+1) LB(b1, j+1)
  }
  MFMAS(a0, b0)
  MFMAS(a1, b1)
  #undef LA
  #undef LB
  #undef MFMAS

  float* out = PG + (size_t)zg*2097152;
  #pragma unroll
  for (int fm = 0; fm < 2; ++fm)
    #pragma unroll
    for (int fn = 0; fn < 4; ++fn)
      #pragma unroll
      for (int r = 0; r < 4; ++r){
        int row = m0 + fm*16 + g*4 + r;
        int col = n0 + fn*16 + ml;
        out[(size_t)row*256 + col] = acc[fm][fn][r];
      }
}

// ---------------- fused angle head + periodic encoding ----------------
// T fp32 (8192,640) cols n=k*64+o. wave per pixel. Writes ang + gateA cols 256..319.
__global__ void k_aph1enc(const float* __restrict__ T, const float* __restrict__ b1,
    const float* __restrict__ w2, const float* __restrict__ b2,
    const float* __restrict__ freq,
    const float* __restrict__ ew1, const float* __restrict__ eb1,
    const float* __restrict__ lng, const float* __restrict__ lnb,
    const float* __restrict__ ew2, const float* __restrict__ eb2,
    float* __restrict__ ang, short* __restrict__ gateA){
  const int KYi[9] = {-1,-1,-1,0,0,0,1,1,1};
  const int KXi[9] = {-1,0,1,-1,0,1,-1,0,1};
  int lane = threadIdx.x & 63;
  int p = blockIdx.x*4 + (threadIdx.x >> 6);
  int hw = p & 4095;
  int h = hw >> 6, w = hw & 63;
  float acc = b1[lane];
  #pragma unroll
  for (int k = 0; k < 9; ++k){
    int y = h + KYi[k], x = w + KXi[k];
    if (y < 0 || y > 63 || x < 0 || x > 63) continue;
    acc += T[(size_t)(p + KYi[k]*64 + KXi[k])*640 + k*64 + lane];
  }
  float av = wsum64(fmaxf(acc, 0.f) * w2[lane]) + b2[0];
  if (lane == 0) ang[p] = av;
  // ---- encode ----
  float an = av * (2.0f / PI_F);
  int f = lane & 31;
  float ph = an * freq[f] * ((float)f * (PI_F / 32.0f));
  float emb = (lane < 32) ? __sinf(ph) : __cosf(ph);
  float hh = eb1[lane];
  const float* w1r = ew1 + lane*64;
  #pragma unroll 8
  for (int i = 0; i < 64; ++i){
    float e = __shfl(emb, i, 64);
    hh = fmaf(e, w1r[i], hh);
  }
  float mu = wsum64(hh) * (1.0f/64.0f);
  float d = hh - mu;
  float var = wsum64(d*d) * (1.0f/64.0f);
  float hn = fmaf(d * rsqrtf(var + 1e-5f), lng[lane], lnb[lane]);
  float r = fmaxf(hn, 0.f);
  float o = eb2[lane];
  const float* w2r = ew2 + lane*64;
  #pragma unroll 8
  for (int i = 0; i < 64; ++i){
    float e = __shfl(r, i, 64);
    o = fmaf(e, w2r[i], o);
  }
  gateA[(size_t)p*320 + 256 + lane] = f2bf(o);
}

// ---------------- bilinear gather on G: 4 px/block, 3 hyps, ushort4, XCD bands --------
__global__ __launch_bounds__(256) void k_sample(const short* __restrict__ G,
    const float* __restrict__ ang, const float* __restrict__ bias,
    short* __restrict__ cand){
  const float KYc[9] = {-1,-1,-1,0,0,0,1,1,1};
  const float KXc[9] = {-1,0,1,-1,0,1,-1,0,1};
  int id = blockIdx.x;
  int sw = (id & 7) * 256 + (id >> 3);
  int p = sw * 4 + (threadIdx.x >> 6);
  int lane = threadIdx.x & 63;
  int c4 = lane * 4;
  int b = p >> 12, hw = p & 4095;
  int h = hw >> 6, w = hw & 63;
  float fh = (float)h, fw = (float)w;
  float a0 = ang[p];
  float4 bs = *(const float4*)(bias + c4);
  float acc[3][4];
  #pragma unroll
  for (int i = 0; i < 3; ++i){
    acc[i][0] = bs.x; acc[i][1] = bs.y; acc[i][2] = bs.z; acc[i][3] = bs.w;
  }
  const short* Gb = G + (size_t)b*HWSZ*2304 + c4;
  #pragma unroll 1
  for (int hyp = 0; hyp < 3; ++hyp){
    float a = a0 + ((float)hyp - 1.0f) * (PI_F / 12.0f);
    float sn = __sinf(a), cs = __cosf(a);
    #pragma unroll
    for (int k = 0; k < 9; ++k){
      float py = fh + KXc[k]*sn + KYc[k]*cs;
      float px = fw + KXc[k]*cs - KYc[k]*sn;
      float y0f = floorf(py), x0f = floorf(px);
      float wy = py - y0f, wx = px - x0f;
      int y0 = (int)y0f, x0 = (int)x0f;
      const short* Gk = Gb + k*256;
      #pragma unroll
      for (int dy = 0; dy < 2; ++dy){
        int yy = y0 + dy;
        if (yy < 0 || yy > 63) continue;
        float fy = dy ? wy : 1.f - wy;
        #pragma unroll
        for (int dx = 0; dx < 2; ++dx){
          int xx = x0 + dx;
          if (xx < 0 || xx > 63) continue;
          float fxy = fy * (dx ? wx : 1.f - wx);
          short4_t v = *(const short4_t*)(Gk + (size_t)(yy*64 + xx)*2304);
          acc[hyp][0] = fmaf(fxy, bf2f(v[0]), acc[hyp][0]);
          acc[hyp][1] = fmaf(fxy, bf2f(v[1]), acc[hyp][1]);
          acc[hyp][2] = fmaf(fxy, bf2f(v[2]), acc[hyp][2]);
          acc[hyp][3] = fmaf(fxy, bf2f(v[3]), acc[hyp][3]);
        }
      }
    }
  }
  #pragma unroll
  for (int hyp = 0; hyp < 3; ++hyp){
    short4_t o;
    #pragma unroll
    for (int j = 0; j < 4; ++j) o[j] = f2bf(acc[hyp][j]);
    *(short4_t*)(cand + ((size_t)hyp*NPIX + p)*256 + c4) = o;
  }
}

// ---------------- attention core ----------------
__global__ void k_attn(const short* __restrict__ Q, const short* __restrict__ KV,
    short* __restrict__ O){
  int lane = threadIdx.x & 63;
  int p = blockIdx.x*4 + (threadIdx.x >> 6);
  float q[4];
  { short4_t t = *(const short4_t*)(Q + (size_t)p*256 + lane*4);
    #pragma unroll
    for (int j = 0; j < 4; ++j) q[j] = bf2f(t[j]); }
  float kv[3][2][4];
  #pragma unroll
  for (int i = 0; i < 3; ++i){
    const short* rp = KV + (size_t)(i*NPIX + p)*512 + lane*4;
    short4_t kt = *(const short4_t*)rp;
    short4_t vt = *(const short4_t*)(rp + 256);
    #pragma unroll
    for (int j = 0; j < 4; ++j){ kv[i][0][j] = bf2f(kt[j]); kv[i][1][j] = bf2f(vt[j]); }
  }
  const float sc = 0.17677669529663688f; // 1/sqrt(32)
  float s[3];
  #pragma unroll
  for (int i = 0; i < 3; ++i){
    float d = 0.f;
    #pragma unroll
    for (int j = 0; j < 4; ++j) d = fmaf(q[j], kv[i][0][j], d);
    s[i] = wsum8(d) * sc;
  }
  float m = fmaxf(s[0], fmaxf(s[1], s[2]));
  float e0 = __expf(s[0]-m), e1 = __expf(s[1]-m), e2 = __expf(s[2]-m);
  float inv = 1.f/(e0+e1+e2);
  short4_t ot;
  #pragma unroll
  for (int j = 0; j < 4; ++j)
    ot[j] = f2bf((e0*kv[0][1][j] + e1*kv[1][1][j] + e2*kv[2][1][j]) * inv);
  *(short4_t*)(O + (size_t)p*256 + lane*4) = ot;
}

// ---------------- sum 3 partials + bias -> t ; per-block GN partial stats ----------------
__global__ void k_sum3stat(const float* __restrict__ PG, const float* __restrict__ bias,
    float* __restrict__ t, float* __restrict__ spart){
  int p0 = blockIdx.x * 8;
  int c = threadIdx.x;
  float bb = bias[c];
  float s = 0.f, s2 = 0.f;
  #pragma unroll
  for (int pp = 0; pp < 8; ++pp){
    size_t idx = (size_t)(p0+pp)*256 + c;
    float v = PG[idx] + PG[idx + 2097152] + PG[idx + 4194304] + bb;
    t[idx] = v;
    s += v; s2 = fmaf(v, v, s2);
  }
  s  += __shfl_xor(s, 1, 64);  s  += __shfl_xor(s, 2, 64);  s  += __shfl_xor(s, 4, 64);
  s2 += __shfl_xor(s2, 1, 64); s2 += __shfl_xor(s2, 2, 64); s2 += __shfl_xor(s2, 4, 64);
  if ((c & 7) == 0){
    int b = p0 >> 12;
    int bg = b*32 + (c >> 3);
    int blk = blockIdx.x & 511;
    spart[(size_t)(bg*512 + blk)*2]     = s;
    spart[(size_t)(bg*512 + blk)*2 + 1] = s2;
  }
}

__global__ void k_gnfin(const float* __restrict__ spart, float* __restrict__ stat){
  int bg = blockIdx.x;
  const float* sp = spart + (size_t)bg*1024;
  float s = 0.f, s2 = 0.f;
  for (int i = threadIdx.x; i < 512; i += 256){
    s += sp[i*2]; s2 += sp[i*2+1];
  }
  s = wsum64(s); s2 = wsum64(s2);
  __shared__ float rs[4], rs2[4];
  int wid = threadIdx.x >> 6;
  if ((threadIdx.x & 63) == 0){ rs[wid] = s; rs2[wid] = s2; }
  __syncthreads();
  if (threadIdx.x == 0){
    float S = rs[0]+rs[1]+rs[2]+rs[3];
    float S2 = rs2[0]+rs2[1]+rs2[2]+rs2[3];
    float mean = S * (1.f/32768.f);
    float var = S2 * (1.f/32768.f) - mean*mean;
    stat[bg*2]   = mean;
    stat[bg*2+1] = rsqrtf(var + 1e-5f);
  }
}

// ---------------- GN + relu -> bf16 (4 px/block, float4) ----------------
__global__ void k_gnrelu(const float* __restrict__ t, const float* __restrict__ stat,
    const float* __restrict__ gng, const float* __restrict__ gnb,
    short* __restrict__ a){
  int p = blockIdx.x*4 + (threadIdx.x >> 6);
  int c4 = (threadIdx.x & 63)*4;
  int b = p >> 12, g = c4 >> 3;
  float mean = stat[(b*32+g)*2], rstd = stat[(b*32+g)*2+1];
  float4 gg = *(const float4*)(gng + c4);
  float4 bb = *(const float4*)(gnb + c4);
  float4 v = *(const float4*)(t + (size_t)p*256 + c4);
  short4_t o;
  o[0] = f2bf(fmaxf((v.x - mean)*rstd*gg.x + bb.x, 0.f));
  o[1] = f2bf(fmaxf((v.y - mean)*rstd*gg.y + bb.y, 0.f));
  o[2] = f2bf(fmaxf((v.z - mean)*rstd*gg.z + bb.z, 0.f));
  o[3] = f2bf(fmaxf((v.w - mean)*rstd*gg.w + bb.w, 0.f));
  *(short4_t*)(a + (size_t)p*256 + c4) = o;
}

// ---------------- launch ----------------
extern "C" void kernel_launch(void* const* d_in, const int* in_sizes, int n_in,
                              void* d_out, int out_size, void* d_ws, size_t ws_size,
                              hipStream_t stream){
  (void)in_sizes; (void)n_in; (void)out_size; (void)ws_size;
  const float* features   = (const float*)d_in[0];
  const float* ap_w1      = (const float*)d_in[1];
  const float* ap_b1      = (const float*)d_in[2];
  const float* ap_w2      = (const float*)d_in[3];
  const float* ap_b2      = (const float*)d_in[4];
  const float* freq       = (const float*)d_in[5];
  const float* ae_w1      = (const float*)d_in[6];
  const float* ae_b1      = (const float*)d_in[7];
  const float* ae_ln_g    = (const float*)d_in[8];
  const float* ae_ln_b    = (const float*)d_in[9];
  const float* ae_w2      = (const float*)d_in[10];
  const float* ae_b2      = (const float*)d_in[11];
  const float* dc_w       = (const float*)d_in[12];
  const float* dc_b       = (const float*)d_in[13];
  const float* attn_in_w  = (const float*)d_in[14];
  const float* attn_in_b  = (const float*)d_in[15];
  const float* attn_out_w = (const float*)d_in[16];
  const float* attn_out_b = (const float*)d_in[17];
  const float* ja_w1      = (const float*)d_in[18];
  const float* ja_b1      = (const float*)d_in[19];
  const float* ja_w2      = (const float*)d_in[20];
  const float* ja_b2      = (const float*)d_in[21];
  const float* op_w1      = (const float*)d_in[22];
  const float* op_b1      = (const float*)d_in[23];
  const float* gn_g       = (const float*)d_in[24];
  const float* gn_b       = (const float*)d_in[25];
  const float* op_w2      = (const float*)d_in[26];
  const float* op_b2      = (const float*)d_in[27];

  char* base = (char*)d_ws;
  #define ALLOC(ty, name, elems) ty* name = (ty*)base; base += (size_t)(elems)*sizeof(ty);
  ALLOC(short, feat_bf, 8192*256)
  ALLOC(short, Bdc,     2304*256)
  ALLOC(short, B2op,    256*2304)
  ALLOC(short, B3ap,    640*768)
  ALLOC(short, inw_bf,  768*256)
  ALLOC(short, wot_bf,  256*256)
  ALLOC(short, jw1_bf,  256*320)
  ALLOC(short, jw2_bf,  256*256)
  ALLOC(short, wop2_bf, 256*256)
  ALLOC(short, Gbuf,    24576*768)   // serves: T_ap(fp32) -> G -> KV/Q -> PG(fp32 x3)
  ALLOC(short, cand_bf, 3*8192*256)  // aliased as A3 (8192x768) before sampling
  ALLOC(short, O_bf,    8192*256)
  ALLOC(short, gateA,   8192*320)
  ALLOC(short, hid_bf,  8192*256)
  ALLOC(short, enh_pad, 2*4356*256)  // (B,66,66,256) zero-padded
  ALLOC(float, angbuf,  8192)
  ALLOC(float, tbuf,    8192*256)
  ALLOC(float, gstat,   128)
  ALLOC(float, spart,   65536)
  ALLOC(short, a_bf,    8192*256)
  #undef ALLOC
  short* A3 = cand_bf;                      // 8192*768, dead before cand written
  float* T_ap = (float*)Gbuf;               // 8192*640 fp32
  short* KVbuf = Gbuf;                      // 24576*512 bf16
  short* Qbuf  = Gbuf + (size_t)24576*512;  // 8192*256 bf16
  float* PG    = (float*)Gbuf;              // 3 x 8192*256 fp32 partials

  dim3 t32(32, 8);
  k_zero4<<<2178, 256, 0, stream>>>(enh_pad, 557568);
  k_nchw_split<<<dim3(128,8,2), t32, 0, stream>>>(features, feat_bf, A3);
  k_prep_tapw<<<256, 256, 0, stream>>>(dc_w,  Bdc);
  k_prep_igw<<<256, 256, 0, stream>>>(op_w1, B2op);
  k_prep_apw3<<<640, 256, 0, stream>>>(ap_w1, B3ap);
  k_castall<<<1856, 256, 0, stream>>>(attn_in_w, attn_out_w, ja_w1, ja_w2, op_w2,
                                      inw_bf, wot_bf, jw1_bf, jw2_bf, wop2_bf);

  // angle head: T = A3 x B3ap^T (compensated bf16, fp32 out), then fused head+encode
  k_gemm<5,64><<<dim3(128,5), 256, 0, stream>>>(A3, B3ap, T_ap, nullptr, nullptr, 768, 640);
  k_aph1enc<<<2048, 256, 0, stream>>>(T_ap, ap_b1, ap_w2, ap_b2, freq,
                                      ae_w1, ae_b1, ae_ln_g, ae_ln_b, ae_w2, ae_b2,
                                      angbuf, gateA);
  // G = feat x Bdc^T (8192,2304) ; sample -> cand
  k_gemm<0,64><<<dim3(128,18), 256, 0, stream>>>(feat_bf, Bdc, Gbuf, nullptr, nullptr, 256, 2304);
  k_sample<<<2048, 256, 0, stream>>>(Gbuf, angbuf, dc_b, cand_bf);
  // KV = cand x in_w[256:768]^T + inb[256:768]  (24576,512)
  k_gemm<1,64><<<dim3(384,4), 256, 0, stream>>>(cand_bf, inw_bf + (size_t)256*256, KVbuf,
                                                attn_in_b + 256, nullptr, 256, 512);
  // Q = cand[hyp1] x in_w[0:256]^T + inb[0:256]  (8192,256)
  k_gemm<1,32><<<dim3(256,2), 256, 0, stream>>>(cand_bf + (size_t)NPIX*256, inw_bf, Qbuf,
                                                attn_in_b, nullptr, 256, 256);
  k_attn<<<2048, 256, 0, stream>>>(Qbuf, KVbuf, O_bf);
  // fused = O x out_w^T + outb -> gateA cols 0..255
  k_gemm<1,32><<<dim3(256,2), 256, 0, stream>>>(O_bf, wot_bf, gateA, attn_out_b, nullptr, 256, 320);
  // hid = relu(gateA x ja_w1^T + b1)
  k_gemm<2,32><<<dim3(256,2), 256, 0, stream>>>(gateA, jw1_bf, hid_bf, ja_b1, nullptr, 320, 256);
  // enh = fused * (1 + sigmoid(hid x ja_w2^T + b2)) -> padded NHWC
  k_gemm<6,32><<<dim3(256,2), 256, 0, stream>>>(hid_bf, jw2_bf, enh_pad, ja_b2, gateA, 256, 256);
  // conv3x3(enh_pad, op_w1): split-K partials then fused sum+bias+GN-stats
  k_igconv<<<dim3(128,2,3), 256, 0, stream>>>(enh_pad, B2op, PG);
  k_sum3stat<<<1024, 256, 0, stream>>>(PG, op_b1, tbuf, spart);
  k_gnfin<<<64, 256, 0, stream>>>(spart, gstat);
  k_gnrelu<<<2048, 256, 0, stream>>>(tbuf, gstat, gn_g, gn_b, a_bf);
  // out = GNrelu x op_w2^T + b2, NCHW fp32
  k_gemm<4,32><<<dim3(256,2), 256, 0, stream>>>(a_bf, wop2_bf, (float*)d_out, op_b2, nullptr, 256, 256);
}

// Round 7
// 248.809 us; speedup vs baseline: 10.3882x; 1.5652x over previous
//
#include <hip/hip_runtime.h>

#define PI_F 3.14159265358979323846f
#define HWSZ 4096   // H*W
#define NPIX 8192   // B*H*W

typedef __attribute__((ext_vector_type(8))) short short8;
typedef __attribute__((ext_vector_type(4))) short short4_t;
typedef __attribute__((ext_vector_type(4))) float f32x4;

__device__ __forceinline__ short f2bf(float x){
  unsigned u = __float_as_uint(x);
  unsigned r = (u + 0x7FFFu + ((u >> 16) & 1u)) >> 16;
  return (short)r;
}
__device__ __forceinline__ float bf2f(short v){
  return __uint_as_float(((unsigned)(unsigned short)v) << 16);
}

__device__ __forceinline__ float wsum64(float v){
  #pragma unroll
  for (int m = 32; m >= 1; m >>= 1) v += __shfl_xor(v, m, 64);
  return v;
}
__device__ __forceinline__ float wsum8(float v){
  v += __shfl_xor(v, 1, 64);
  v += __shfl_xor(v, 2, 64);
  v += __shfl_xor(v, 4, 64);
  return v;
}

// async global->LDS, 16B per lane. dst must be wave-uniform-base + lane*16 (it is).
__device__ __forceinline__ void gl_lds(const short* g, short* s){
  __builtin_amdgcn_global_load_lds(
      (const __attribute__((address_space(1))) unsigned int*)g,
      (__attribute__((address_space(3))) unsigned int*)s, 16, 0, 0);
}

// ---------------- prep kernels ----------------
__global__ void k_zero4(short* __restrict__ p, int n4){
  int i = blockIdx.x*256 + threadIdx.x;
  if (i < n4) ((short4_t*)p)[i] = (short4_t){0,0,0,0};
}

// features (B,256,H,W) -> feat_bf (B,H,W,256) hi ; A3 (p,768)=[hi|hi|lo]
__global__ void k_nchw_split(const float* __restrict__ in, short* __restrict__ feat_bf,
    short* __restrict__ A3){
  __shared__ float tile[32][33];
  int b = blockIdx.z;
  int p0 = blockIdx.x * 32, c0 = blockIdx.y * 32;
  int tx = threadIdx.x, ty = threadIdx.y;
  #pragma unroll
  for (int i = ty; i < 32; i += 8)
    tile[i][tx] = in[((size_t)b*256 + c0 + i)*HWSZ + p0 + tx];
  __syncthreads();
  #pragma unroll
  for (int i = ty; i < 32; i += 8){
    float x = tile[tx][i];
    short hi = f2bf(x);
    short lo = f2bf(x - bf2f(hi));
    size_t p = (size_t)b*HWSZ + p0 + i;
    feat_bf[p*256 + c0 + tx] = hi;
    A3[p*768 + c0 + tx] = hi;
    A3[p*768 + 256 + c0 + tx] = hi;
    A3[p*768 + 512 + c0 + tx] = lo;
  }
}

// 3x3 conv weight (O,C,9) -> bf16 B[n=k*256+o][c] (tap-major GEMM B)
__global__ void k_prep_tapw(const float* __restrict__ w, short* __restrict__ Bm){
  __shared__ short tile[9][256];
  int o = blockIdx.x;
  const float* wo = w + (size_t)o*2304;
  for (int i = threadIdx.x; i < 2304; i += 256){
    int c = i / 9, k = i - c*9;
    tile[k][c] = f2bf(wo[i]);
  }
  __syncthreads();
  for (int i = threadIdx.x; i < 2304; i += 256){
    int k = i >> 8, c = i & 255;
    Bm[((size_t)(k*256 + o))*256 + c] = tile[k][c];
  }
}

// 3x3 conv weight (O,C,9) -> bf16 B2[o][k*256+c] (implicit-GEMM conv B)
__global__ void k_prep_igw(const float* __restrict__ w, short* __restrict__ B2){
  __shared__ short tile[2304];
  int o = blockIdx.x;
  const float* wo = w + (size_t)o*2304;
  for (int i = threadIdx.x; i < 2304; i += 256){
    int c = i / 9, k = i - c*9;
    tile[k*256 + c] = f2bf(wo[i]);
  }
  __syncthreads();
  short* out = B2 + (size_t)o*2304;
  for (int i = threadIdx.x; i < 2304; i += 256) out[i] = tile[i];
}

// ap_w1 (64,256,3,3) -> B3 (640,768) = [Bh|Bl|Bh], rows n=k*64+o, zero-pad n>=576
__global__ void k_prep_apw3(const float* __restrict__ w, short* __restrict__ B3){
  int n = blockIdx.x, c = threadIdx.x;
  short hi = 0, lo = 0;
  if (n < 576){
    int o = n & 63, k = n >> 6;
    float x = w[((size_t)o*256 + c)*9 + k];
    hi = f2bf(x);
    lo = f2bf(x - bf2f(hi));
  }
  B3[(size_t)n*768 + c] = hi;
  B3[(size_t)n*768 + 256 + c] = lo;
  B3[(size_t)n*768 + 512 + c] = hi;
}

// all 5 small weights cast in one launch
__global__ void k_castall(const float* __restrict__ s0, const float* __restrict__ s1,
    const float* __restrict__ s2, const float* __restrict__ s3, const float* __restrict__ s4,
    short* __restrict__ d0, short* __restrict__ d1, short* __restrict__ d2,
    short* __restrict__ d3, short* __restrict__ d4){
  int i = blockIdx.x*256 + threadIdx.x;
  if (i < 196608) d0[i] = f2bf(s0[i]);
  else if (i < 262144) d1[i-196608] = f2bf(s1[i-196608]);
  else if (i < 344064) d2[i-262144] = f2bf(s2[i-262144]);
  else if (i < 409600) d3[i-344064] = f2bf(s3[i-344064]);
  else if (i < 475136) d4[i-409600] = f2bf(s4[i-409600]);
}

// ---------------- LDS-staged bf16 TN GEMM (m97 structure) ----------------
// C[M][*] = A[M][K] x B[N][K]^T. BN=128, BK=32, dbuf LDS via global_load_lds w16.
// 4 waves 2x2: wave tile (BM/2) x 64.
// EPI: 0 bf16; 1 bf16+bias; 2 bf16 relu+bias; 3 gate->linear; 4 fp32 NCHW +bias;
//      5 fp32 plain; 6 gate->padded NHWC
template<int EPI, int BM>
__global__ __launch_bounds__(256) void k_gemml(const short* __restrict__ A,
    const short* __restrict__ B, void* __restrict__ Cv,
    const float* __restrict__ bias, const short* __restrict__ aux,
    int K, int ldc){
  constexpr int WM = BM/2;
  constexpr int AF = WM/16;
  __shared__ alignas(16) short sA[2][BM*32];
  __shared__ alignas(16) short sB[2][128*32];
  int tid = threadIdx.x;
  int w = tid >> 6, l = tid & 63;
  int wr = w & 1, wc = w >> 1;
  int ml = l & 15, g = l >> 4;
  int srow = tid >> 2;
  int sch = (tid & 3)*8;
  int m0 = blockIdx.x*BM, n0 = blockIdx.y*128;
  const short* Agp = A + (size_t)(m0 + srow)*K + sch;
  const short* Bgp = B + (size_t)(n0 + srow)*K + sch;
  short* sAd = &sA[0][srow*32 + sch];
  short* sBd = &sB[0][srow*32 + sch];
  f32x4 acc[AF][4];
  #pragma unroll
  for (int i = 0; i < AF; ++i)
    #pragma unroll
    for (int j = 0; j < 4; ++j) acc[i][j] = (f32x4){0.f,0.f,0.f,0.f};

  #define STAGE(bf, kt) { \
    _Pragma("unroll") \
    for (int c = 0; c < BM/64; ++c) \
      gl_lds(Agp + (size_t)(c*64)*K + (kt)*32, sAd + (bf)*BM*32 + c*2048); \
    _Pragma("unroll") \
    for (int c = 0; c < 2; ++c) \
      gl_lds(Bgp + (size_t)(c*64)*K + (kt)*32, sBd + (bf)*4096 + c*2048); \
  }
  int nk = K >> 5;
  STAGE(0, 0)
  int buf = 0;
  for (int kt = 0; kt < nk; ++kt){
    __syncthreads();            // staged tile visible; prior reads of buf^1 done
    if (kt + 1 < nk){ STAGE(buf^1, kt+1) }
    short8 af[AF], bq[4];
    #pragma unroll
    for (int i = 0; i < AF; ++i)
      af[i] = *(const short8*)&sA[buf][(wr*WM + i*16 + ml)*32 + g*8];
    #pragma unroll
    for (int j = 0; j < 4; ++j)
      bq[j] = *(const short8*)&sB[buf][(wc*64 + j*16 + ml)*32 + g*8];
    #pragma unroll
    for (int i = 0; i < AF; ++i)
      #pragma unroll
      for (int j = 0; j < 4; ++j)
        acc[i][j] = __builtin_amdgcn_mfma_f32_16x16x32_bf16(af[i], bq[j], acc[i][j], 0, 0, 0);
    buf ^= 1;
  }
  #undef STAGE

  int m0w = m0 + wr*WM;
  int n0w = n0 + wc*64;
  if constexpr (EPI == 4){
    __shared__ float cst[BM][129];
    #pragma unroll
    for (int fm = 0; fm < AF; ++fm)
      #pragma unroll
      for (int fn = 0; fn < 4; ++fn)
        #pragma unroll
        for (int r = 0; r < 4; ++r){
          int cl = wc*64 + fn*16 + ml;
          cst[wr*WM + fm*16 + g*4 + r][cl] = acc[fm][fn][r] + bias[blockIdx.y*128 + cl];
        }
    __syncthreads();
    int px0 = blockIdx.x*BM;
    int b = px0 >> 12, hw0 = px0 & 4095;
    int o = tid >> 1, seg = (tid & 1)*(BM/2);
    float* op = (float*)Cv + (((size_t)(b*256 + blockIdx.y*128 + o)) << 12) + hw0 + seg;
    #pragma unroll
    for (int i = 0; i < BM/2; i += 4){
      float4 vv = {cst[seg+i][o], cst[seg+i+1][o], cst[seg+i+2][o], cst[seg+i+3][o]};
      *(float4*)(op + i) = vv;
    }
  } else {
    #pragma unroll
    for (int fm = 0; fm < AF; ++fm)
      #pragma unroll
      for (int fn = 0; fn < 4; ++fn)
        #pragma unroll
        for (int r = 0; r < 4; ++r){
          int row = m0w + fm*16 + g*4 + r;
          int col = n0w + fn*16 + ml;
          float v = acc[fm][fn][r];
          if constexpr (EPI == 0){
            ((short*)Cv)[(size_t)row*ldc + col] = f2bf(v);
          } else if constexpr (EPI == 1){
            ((short*)Cv)[(size_t)row*ldc + col] = f2bf(v + bias[col]);
          } else if constexpr (EPI == 2){
            ((short*)Cv)[(size_t)row*ldc + col] = f2bf(fmaxf(v + bias[col], 0.f));
          } else if constexpr (EPI == 3){
            float f = bf2f(aux[(size_t)row*320 + col]);
            float s = 1.f/(1.f + __expf(-(v + bias[col])));
            ((short*)Cv)[(size_t)row*ldc + col] = f2bf(f * (1.f + s));
          } else if constexpr (EPI == 6){
            float f = bf2f(aux[(size_t)row*320 + col]);
            float s = 1.f/(1.f + __expf(-(v + bias[col])));
            int b = row >> 12, hw = row & 4095;
            int pi = b*4356 + ((hw>>6)+1)*66 + (hw&63) + 1;
            ((short*)Cv)[(size_t)pi*256 + col] = f2bf(f * (1.f + s));
          } else {
            ((float*)Cv)[(size_t)row*ldc + col] = v;
          }
        }
  }
}

// ---------------- implicit-GEMM 3x3 conv, LDS-staged, split-K by tap group ----------
// grid (128, 2, 3). PG[z][p][o] = sum over taps 3z..3z+2. Xpad (B,66,66,256) bf16.
__global__ __launch_bounds__(256) void k_igconv(const short* __restrict__ Xpad,
    const short* __restrict__ B2, float* __restrict__ PG){
  __shared__ alignas(16) short sA[2][64*32];
  __shared__ alignas(16) short sB[2][128*32];
  int zg = blockIdx.z;
  int tid = threadIdx.x;
  int w = tid >> 6, l = tid & 63;
  int wr = w & 1, wc = w >> 1;
  int ml = l & 15, g = l >> 4;
  int srow = tid >> 2;
  int sch = (tid & 3)*8;
  int m0 = blockIdx.x*64, n0 = blockIdx.y*128;
  int b = blockIdx.x >> 6, imgrow = blockIdx.x & 63;
  int qbase = b*4356 + (imgrow+1)*66 + srow + 1;
  const short* Bgp = B2 + (size_t)(n0 + srow)*2304 + zg*768 + sch;
  short* sAd = &sA[0][srow*32 + sch];
  short* sBd = &sB[0][srow*32 + sch];
  int toff[3];
  #pragma unroll
  for (int i = 0; i < 3; ++i){
    int t = zg*3 + i;
    toff[i] = (t/3 - 1)*66 + (t%3) - 1;
  }
  f32x4 acc[2][4];
  #pragma unroll
  for (int i = 0; i < 2; ++i)
    #pragma unroll
    for (int j = 0; j < 4; ++j) acc[i][j] = (f32x4){0.f,0.f,0.f,0.f};

  #define STG(bf, kt) { \
    int tap = (kt) >> 3, cofs = ((kt) & 7)*32; \
    gl_lds(Xpad + (size_t)(qbase + toff[tap])*256 + cofs + sch, sAd + (bf)*2048); \
    gl_lds(Bgp + (kt)*32, sBd + (bf)*4096); \
    gl_lds(Bgp + (size_t)64*2304 + (kt)*32, sBd + (bf)*4096 + 2048); \
  }
  STG(0, 0)
  int buf = 0;
  for (int kt = 0; kt < 24; ++kt){
    __syncthreads();
    if (kt < 23){ STG(buf^1, kt+1) }
    short8 af[2], bq[4];
    #pragma unroll
    for (int i = 0; i < 2; ++i)
      af[i] = *(const short8*)&sA[buf][(wr*32 + i*16 + ml)*32 + g*8];
    #pragma unroll
    for (int j = 0; j < 4; ++j)
      bq[j] = *(const short8*)&sB[buf][(wc*64 + j*16 + ml)*32 + g*8];
    #pragma unroll
    for (int i = 0; i < 2; ++i)
      #pragma unroll
      for (int j = 0; j < 4; ++j)
        acc[i][j] = __builtin_amdgcn_mfma_f32_16x16x32_bf16(af[i], bq[j], acc[i][j], 0, 0, 0);
    buf ^= 1;
  }
  #undef STG

  float* out = PG + (size_t)zg*2097152;
  int m0w = m0 + wr*32;
  int n0w = n0 + wc*64;
  #pragma unroll
  for (int fm = 0; fm < 2; ++fm)
    #pragma unroll
    for (int fn = 0; fn < 4; ++fn)
      #pragma unroll
      for (int r = 0; r < 4; ++r){
        int row = m0w + fm*16 + g*4 + r;
        int col = n0w + fn*16 + ml;
        out[(size_t)row*256 + col] = acc[fm][fn][r];
      }
}

// ---------------- fused angle head + periodic encoding ----------------
__global__ void k_aph1enc(const float* __restrict__ T, const float* __restrict__ b1,
    const float* __restrict__ w2, const float* __restrict__ b2,
    const float* __restrict__ freq,
    const float* __restrict__ ew1, const float* __restrict__ eb1,
    const float* __restrict__ lng, const float* __restrict__ lnb,
    const float* __restrict__ ew2, const float* __restrict__ eb2,
    float* __restrict__ ang, short* __restrict__ gateA){
  const int KYi[9] = {-1,-1,-1,0,0,0,1,1,1};
  const int KXi[9] = {-1,0,1,-1,0,1,-1,0,1};
  int lane = threadIdx.x & 63;
  int p = blockIdx.x*4 + (threadIdx.x >> 6);
  int hw = p & 4095;
  int h = hw >> 6, w = hw & 63;
  float acc = b1[lane];
  #pragma unroll
  for (int k = 0; k < 9; ++k){
    int y = h + KYi[k], x = w + KXi[k];
    if (y < 0 || y > 63 || x < 0 || x > 63) continue;
    acc += T[(size_t)(p + KYi[k]*64 + KXi[k])*640 + k*64 + lane];
  }
  float av = wsum64(fmaxf(acc, 0.f) * w2[lane]) + b2[0];
  if (lane == 0) ang[p] = av;
  float an = av * (2.0f / PI_F);
  int f = lane & 31;
  float ph = an * freq[f] * ((float)f * (PI_F / 32.0f));
  float emb = (lane < 32) ? __sinf(ph) : __cosf(ph);
  float hh = eb1[lane];
  const float* w1r = ew1 + lane*64;
  #pragma unroll 8
  for (int i = 0; i < 64; ++i){
    float e = __shfl(emb, i, 64);
    hh = fmaf(e, w1r[i], hh);
  }
  float mu = wsum64(hh) * (1.0f/64.0f);
  float d = hh - mu;
  float var = wsum64(d*d) * (1.0f/64.0f);
  float hn = fmaf(d * rsqrtf(var + 1e-5f), lng[lane], lnb[lane]);
  float r = fmaxf(hn, 0.f);
  float o = eb2[lane];
  const float* w2r = ew2 + lane*64;
  #pragma unroll 8
  for (int i = 0; i < 64; ++i){
    float e = __shfl(r, i, 64);
    o = fmaf(e, w2r[i], o);
  }
  gateA[(size_t)p*320 + 256 + lane] = f2bf(o);
}

// ---------------- bilinear gather on G: 4 px/block, 3 hyps, ushort4, XCD bands --------
__global__ __launch_bounds__(256) void k_sample(const short* __restrict__ G,
    const float* __restrict__ ang, const float* __restrict__ bias,
    short* __restrict__ cand){
  const float KYc[9] = {-1,-1,-1,0,0,0,1,1,1};
  const float KXc[9] = {-1,0,1,-1,0,1,-1,0,1};
  int id = blockIdx.x;
  int sw = (id & 7) * 256 + (id >> 3);
  int p = sw * 4 + (threadIdx.x >> 6);
  int lane = threadIdx.x & 63;
  int c4 = lane * 4;
  int b = p >> 12, hw = p & 4095;
  int h = hw >> 6, w = hw & 63;
  float fh = (float)h, fw = (float)w;
  float a0 = ang[p];
  float4 bs = *(const float4*)(bias + c4);
  float acc[3][4];
  #pragma unroll
  for (int i = 0; i < 3; ++i){
    acc[i][0] = bs.x; acc[i][1] = bs.y; acc[i][2] = bs.z; acc[i][3] = bs.w;
  }
  const short* Gb = G + (size_t)b*HWSZ*2304 + c4;
  #pragma unroll 1
  for (int hyp = 0; hyp < 3; ++hyp){
    float a = a0 + ((float)hyp - 1.0f) * (PI_F / 12.0f);
    float sn = __sinf(a), cs = __cosf(a);
    #pragma unroll
    for (int k = 0; k < 9; ++k){
      float py = fh + KXc[k]*sn + KYc[k]*cs;
      float px = fw + KXc[k]*cs - KYc[k]*sn;
      float y0f = floorf(py), x0f = floorf(px);
      float wy = py - y0f, wx = px - x0f;
      int y0 = (int)y0f, x0 = (int)x0f;
      const short* Gk = Gb + k*256;
      #pragma unroll
      for (int dy = 0; dy < 2; ++dy){
        int yy = y0 + dy;
        if (yy < 0 || yy > 63) continue;
        float fy = dy ? wy : 1.f - wy;
        #pragma unroll
        for (int dx = 0; dx < 2; ++dx){
          int xx = x0 + dx;
          if (xx < 0 || xx > 63) continue;
          float fxy = fy * (dx ? wx : 1.f - wx);
          short4_t v = *(const short4_t*)(Gk + (size_t)(yy*64 + xx)*2304);
          acc[hyp][0] = fmaf(fxy, bf2f(v[0]), acc[hyp][0]);
          acc[hyp][1] = fmaf(fxy, bf2f(v[1]), acc[hyp][1]);
          acc[hyp][2] = fmaf(fxy, bf2f(v[2]), acc[hyp][2]);
          acc[hyp][3] = fmaf(fxy, bf2f(v[3]), acc[hyp][3]);
        }
      }
    }
  }
  #pragma unroll
  for (int hyp = 0; hyp < 3; ++hyp){
    short4_t o;
    #pragma unroll
    for (int j = 0; j < 4; ++j) o[j] = f2bf(acc[hyp][j]);
    *(short4_t*)(cand + ((size_t)hyp*NPIX + p)*256 + c4) = o;
  }
}

// ---------------- attention core ----------------
__global__ void k_attn(const short* __restrict__ Q, const short* __restrict__ KV,
    short* __restrict__ O){
  int lane = threadIdx.x & 63;
  int p = blockIdx.x*4 + (threadIdx.x >> 6);
  float q[4];
  { short4_t t = *(const short4_t*)(Q + (size_t)p*256 + lane*4);
    #pragma unroll
    for (int j = 0; j < 4; ++j) q[j] = bf2f(t[j]); }
  float kv[3][2][4];
  #pragma unroll
  for (int i = 0; i < 3; ++i){
    const short* rp = KV + (size_t)(i*NPIX + p)*512 + lane*4;
    short4_t kt = *(const short4_t*)rp;
    short4_t vt = *(const short4_t*)(rp + 256);
    #pragma unroll
    for (int j = 0; j < 4; ++j){ kv[i][0][j] = bf2f(kt[j]); kv[i][1][j] = bf2f(vt[j]); }
  }
  const float sc = 0.17677669529663688f; // 1/sqrt(32)
  float s[3];
  #pragma unroll
  for (int i = 0; i < 3; ++i){
    float d = 0.f;
    #pragma unroll
    for (int j = 0; j < 4; ++j) d = fmaf(q[j], kv[i][0][j], d);
    s[i] = wsum8(d) * sc;
  }
  float m = fmaxf(s[0], fmaxf(s[1], s[2]));
  float e0 = __expf(s[0]-m), e1 = __expf(s[1]-m), e2 = __expf(s[2]-m);
  float inv = 1.f/(e0+e1+e2);
  short4_t ot;
  #pragma unroll
  for (int j = 0; j < 4; ++j)
    ot[j] = f2bf((e0*kv[0][1][j] + e1*kv[1][1][j] + e2*kv[2][1][j]) * inv);
  *(short4_t*)(O + (size_t)p*256 + lane*4) = ot;
}

// ---------------- sum 3 partials + bias -> t ; per-block GN partial stats ----------------
__global__ void k_sum3stat(const float* __restrict__ PG, const float* __restrict__ bias,
    float* __restrict__ t, float* __restrict__ spart){
  int p0 = blockIdx.x * 8;
  int c = threadIdx.x;
  float bb = bias[c];
  float s = 0.f, s2 = 0.f;
  #pragma unroll
  for (int pp = 0; pp < 8; ++pp){
    size_t idx = (size_t)(p0+pp)*256 + c;
    float v = PG[idx] + PG[idx + 2097152] + PG[idx + 4194304] + bb;
    t[idx] = v;
    s += v; s2 = fmaf(v, v, s2);
  }
  s  += __shfl_xor(s, 1, 64);  s  += __shfl_xor(s, 2, 64);  s  += __shfl_xor(s, 4, 64);
  s2 += __shfl_xor(s2, 1, 64); s2 += __shfl_xor(s2, 2, 64); s2 += __shfl_xor(s2, 4, 64);
  if ((c & 7) == 0){
    int b = p0 >> 12;
    int bg = b*32 + (c >> 3);
    int blk = blockIdx.x & 511;
    spart[(size_t)(bg*512 + blk)*2]     = s;
    spart[(size_t)(bg*512 + blk)*2 + 1] = s2;
  }
}

__global__ void k_gnfin(const float* __restrict__ spart, float* __restrict__ stat){
  int bg = blockIdx.x;
  const float* sp = spart + (size_t)bg*1024;
  float s = 0.f, s2 = 0.f;
  for (int i = threadIdx.x; i < 512; i += 256){
    s += sp[i*2]; s2 += sp[i*2+1];
  }
  s = wsum64(s); s2 = wsum64(s2);
  __shared__ float rs[4], rs2[4];
  int wid = threadIdx.x >> 6;
  if ((threadIdx.x & 63) == 0){ rs[wid] = s; rs2[wid] = s2; }
  __syncthreads();
  if (threadIdx.x == 0){
    float S = rs[0]+rs[1]+rs[2]+rs[3];
    float S2 = rs2[0]+rs2[1]+rs2[2]+rs2[3];
    float mean = S * (1.f/32768.f);
    float var = S2 * (1.f/32768.f) - mean*mean;
    stat[bg*2]   = mean;
    stat[bg*2+1] = rsqrtf(var + 1e-5f);
  }
}

// ---------------- GN + relu -> bf16 (4 px/block, float4) ----------------
__global__ void k_gnrelu(const float* __restrict__ t, const float* __restrict__ stat,
    const float* __restrict__ gng, const float* __restrict__ gnb,
    short* __restrict__ a){
  int p = blockIdx.x*4 + (threadIdx.x >> 6);
  int c4 = (threadIdx.x & 63)*4;
  int b = p >> 12, g = c4 >> 3;
  float mean = stat[(b*32+g)*2], rstd = stat[(b*32+g)*2+1];
  float4 gg = *(const float4*)(gng + c4);
  float4 bb = *(const float4*)(gnb + c4);
  float4 v = *(const float4*)(t + (size_t)p*256 + c4);
  short4_t o;
  o[0] = f2bf(fmaxf((v.x - mean)*rstd*gg.x + bb.x, 0.f));
  o[1] = f2bf(fmaxf((v.y - mean)*rstd*gg.y + bb.y, 0.f));
  o[2] = f2bf(fmaxf((v.z - mean)*rstd*gg.z + bb.z, 0.f));
  o[3] = f2bf(fmaxf((v.w - mean)*rstd*gg.w + bb.w, 0.f));
  *(short4_t*)(a + (size_t)p*256 + c4) = o;
}

// ---------------- launch ----------------
extern "C" void kernel_launch(void* const* d_in, const int* in_sizes, int n_in,
                              void* d_out, int out_size, void* d_ws, size_t ws_size,
                              hipStream_t stream){
  (void)in_sizes; (void)n_in; (void)out_size; (void)ws_size;
  const float* features   = (const float*)d_in[0];
  const float* ap_w1      = (const float*)d_in[1];
  const float* ap_b1      = (const float*)d_in[2];
  const float* ap_w2      = (const float*)d_in[3];
  const float* ap_b2      = (const float*)d_in[4];
  const float* freq       = (const float*)d_in[5];
  const float* ae_w1      = (const float*)d_in[6];
  const float* ae_b1      = (const float*)d_in[7];
  const float* ae_ln_g    = (const float*)d_in[8];
  const float* ae_ln_b    = (const float*)d_in[9];
  const float* ae_w2      = (const float*)d_in[10];
  const float* ae_b2      = (const float*)d_in[11];
  const float* dc_w       = (const float*)d_in[12];
  const float* dc_b       = (const float*)d_in[13];
  const float* attn_in_w  = (const float*)d_in[14];
  const float* attn_in_b  = (const float*)d_in[15];
  const float* attn_out_w = (const float*)d_in[16];
  const float* attn_out_b = (const float*)d_in[17];
  const float* ja_w1      = (const float*)d_in[18];
  const float* ja_b1      = (const float*)d_in[19];
  const float* ja_w2      = (const float*)d_in[20];
  const float* ja_b2      = (const float*)d_in[21];
  const float* op_w1      = (const float*)d_in[22];
  const float* op_b1      = (const float*)d_in[23];
  const float* gn_g       = (const float*)d_in[24];
  const float* gn_b       = (const float*)d_in[25];
  const float* op_w2      = (const float*)d_in[26];
  const float* op_b2      = (const float*)d_in[27];

  char* base = (char*)d_ws;
  #define ALLOC(ty, name, elems) ty* name = (ty*)base; base += (size_t)(elems)*sizeof(ty);
  ALLOC(short, feat_bf, 8192*256)
  ALLOC(short, Bdc,     2304*256)
  ALLOC(short, B2op,    256*2304)
  ALLOC(short, B3ap,    640*768)
  ALLOC(short, inw_bf,  768*256)
  ALLOC(short, wot_bf,  256*256)
  ALLOC(short, jw1_bf,  256*320)
  ALLOC(short, jw2_bf,  256*256)
  ALLOC(short, wop2_bf, 256*256)
  ALLOC(short, Gbuf,    24576*768)   // serves: T_ap(fp32) -> G -> KV/Q -> PG(fp32 x3)
  ALLOC(short, cand_bf, 3*8192*256)  // aliased as A3 (8192x768) before sampling
  ALLOC(short, O_bf,    8192*256)
  ALLOC(short, gateA,   8192*320)
  ALLOC(short, hid_bf,  8192*256)
  ALLOC(short, enh_pad, 2*4356*256)  // (B,66,66,256) zero-padded
  ALLOC(float, angbuf,  8192)
  ALLOC(float, tbuf,    8192*256)
  ALLOC(float, gstat,   128)
  ALLOC(float, spart,   65536)
  ALLOC(short, a_bf,    8192*256)
  #undef ALLOC
  short* A3 = cand_bf;                      // 8192*768, dead before cand written
  float* T_ap = (float*)Gbuf;               // 8192*640 fp32
  short* KVbuf = Gbuf;                      // 24576*512 bf16
  short* Qbuf  = Gbuf + (size_t)24576*512;  // 8192*256 bf16
  float* PG    = (float*)Gbuf;              // 3 x 8192*256 fp32 partials

  dim3 t32(32, 8);
  k_zero4<<<2178, 256, 0, stream>>>(enh_pad, 557568);
  k_nchw_split<<<dim3(128,8,2), t32, 0, stream>>>(features, feat_bf, A3);
  k_prep_tapw<<<256, 256, 0, stream>>>(dc_w,  Bdc);
  k_prep_igw<<<256, 256, 0, stream>>>(op_w1, B2op);
  k_prep_apw3<<<640, 256, 0, stream>>>(ap_w1, B3ap);
  k_castall<<<1856, 256, 0, stream>>>(attn_in_w, attn_out_w, ja_w1, ja_w2, op_w2,
                                      inw_bf, wot_bf, jw1_bf, jw2_bf, wop2_bf);

  // angle head: T = A3 x B3ap^T (compensated bf16, fp32 out), then fused head+encode
  k_gemml<5,64><<<dim3(128,5), 256, 0, stream>>>(A3, B3ap, T_ap, nullptr, nullptr, 768, 640);
  k_aph1enc<<<2048, 256, 0, stream>>>(T_ap, ap_b1, ap_w2, ap_b2, freq,
                                      ae_w1, ae_b1, ae_ln_g, ae_ln_b, ae_w2, ae_b2,
                                      angbuf, gateA);
  // G = feat x Bdc^T (8192,2304) ; sample -> cand
  k_gemml<0,128><<<dim3(64,18), 256, 0, stream>>>(feat_bf, Bdc, Gbuf, nullptr, nullptr, 256, 2304);
  k_sample<<<2048, 256, 0, stream>>>(Gbuf, angbuf, dc_b, cand_bf);
  // KV = cand x in_w[256:768]^T + inb[256:768]  (24576,512)
  k_gemml<1,128><<<dim3(192,4), 256, 0, stream>>>(cand_bf, inw_bf + (size_t)256*256, KVbuf,
                                                  attn_in_b + 256, nullptr, 256, 512);
  // Q = cand[hyp1] x in_w[0:256]^T + inb[0:256]  (8192,256)
  k_gemml<1,64><<<dim3(128,2), 256, 0, stream>>>(cand_bf + (size_t)NPIX*256, inw_bf, Qbuf,
                                                 attn_in_b, nullptr, 256, 256);
  k_attn<<<2048, 256, 0, stream>>>(Qbuf, KVbuf, O_bf);
  // fused = O x out_w^T + outb -> gateA cols 0..255
  k_gemml<1,64><<<dim3(128,2), 256, 0, stream>>>(O_bf, wot_bf, gateA, attn_out_b, nullptr, 256, 320);
  // hid = relu(gateA x ja_w1^T + b1)
  k_gemml<2,64><<<dim3(128,2), 256, 0, stream>>>(gateA, jw1_bf, hid_bf, ja_b1, nullptr, 320, 256);
  // enh = fused * (1 + sigmoid(hid x ja_w2^T + b2)) -> padded NHWC
  k_gemml<6,64><<<dim3(128,2), 256, 0, stream>>>(hid_bf, jw2_bf, enh_pad, ja_b2, gateA, 256, 256);
  // conv3x3(enh_pad, op_w1): LDS-staged split-K partials then fused sum+bias+GN-stats
  k_igconv<<<dim3(128,2,3), 256, 0, stream>>>(enh_pad, B2op, PG);
  k_sum3stat<<<1024, 256, 0, stream>>>(PG, op_b1, tbuf, spart);
  k_gnfin<<<64, 256, 0, stream>>>(spart, gstat);
  k_gnrelu<<<2048, 256, 0, stream>>>(tbuf, gstat, gn_g, gn_b, a_bf);
  // out = GNrelu x op_w2^T + b2, NCHW fp32
  k_gemml<4,64><<<dim3(128,2), 256, 0, stream>>>(a_bf, wop2_bf, (float*)d_out, op_b2, nullptr, 256, 256);
}